// Round 8
// baseline (430.802 us; speedup 1.0000x reference)
//
#include <hip/hip_runtime.h>
#include <hip/hip_bf16.h>

// VectorQuantizer: z [8,64,64,64] fp32 (BCHW), embedding [8192,64] fp32.
// Outputs (concat): z_q [8,64,64,64] fp32 (BCHW), indices [32768] as fp32.
//
// R8: k_mfma was LDS-pipe-bound (R7: per-CU LDS ~102us + 27us conflicts vs
// MFMA 49.7us; MfmaUtil 23%). Changes:
//  - 2 pixel-sets per wave: 4 B-fragment reads feed 12 MFMAs (was 6) -> LDS/MFMA halved
//  - B staged in MFMA-fragment order: reads are lane*16 contiguous (conflict-free);
//    staging writes granule-distinct (kills 1.7e7 conflict cycles)
//  - fused prep kernel; k_apply folded into k_finalize via flag bit 31 of idx_arr

#define NPIX 32768
#define NE   8192
#define EDIM 64
#define HW   4096
#define NSTAGE 64          // codes per LDS stage (4 subtiles of 16)
#define MARGIN 2.0e-4f

typedef short bf16x8 __attribute__((ext_vector_type(8)));
typedef float f32x4  __attribute__((ext_vector_type(4)));

__device__ __forceinline__ short f2bf_bits(float x) {
    __hip_bfloat16 h = __float2bfloat16(x);
    short s; __builtin_memcpy(&s, &h, 2); return s;
}
__device__ __forceinline__ float bf_hi_f(float x) {
    return __bfloat162float(__float2bfloat16(x));
}
// map float to unsigned with same total order
__device__ __forceinline__ unsigned int order_u32(float f) {
    unsigned int s = __float_as_uint(f);
    return (s & 0x80000000u) ? ~s : (s | 0x80000000u);
}

// ---------------- prep (fused): codebook part + pixel part -------------------
__global__ __launch_bounds__(256) void k_prep(const float* __restrict__ emb,
                                              const float* __restrict__ z,
                                              float* __restrict__ e_norm,
                                              float* __restrict__ se_half,
                                              short* __restrict__ eh,
                                              short* __restrict__ el,
                                              float* __restrict__ zn) {
    if (blockIdx.x < NE / 4) {
        // --- codebook: 1 code per wave ---
        const int wave = threadIdx.x >> 6;
        const int lane = threadIdx.x & 63;       // = channel
        const int n = blockIdx.x * 4 + wave;
        float v = emb[n * EDIM + lane];
        float ss = v * v;
        #pragma unroll
        for (int off = 32; off; off >>= 1) ss += __shfl_xor(ss, off, 64);
        const float inv = 1.0f / fmaxf(sqrtf(ss), 1e-12f);
        const float en = v * inv;
        e_norm[n * EDIM + lane] = en;
        const float hf = bf_hi_f(en);
        eh[n * EDIM + lane] = f2bf_bits(en);
        el[n * EDIM + lane] = f2bf_bits(en - hf);
        float s2 = en * en;
        #pragma unroll
        for (int off = 32; off; off >>= 1) s2 += __shfl_xor(s2, off, 64);
        if (lane == 0) se_half[n] = 0.5f * s2;
    } else {
        // --- pixels: normalize -> zn fp32 row-major [p][c] ---
        const int p = (blockIdx.x - NE / 4) * 256 + threadIdx.x;
        const int b = p >> 12, hw = p & (HW - 1);
        const float* zp = z + b * (EDIM * HW) + hw;
        float ss = 0.0f;
        for (int c = 0; c < EDIM; ++c) { const float v = zp[c * HW]; ss = fmaf(v, v, ss); }
        const float inv = 1.0f / fmaxf(sqrtf(ss), 1e-12f);
        for (int c4 = 0; c4 < 16; ++c4) {
            float4 o;
            o.x = zp[(c4 * 4 + 0) * HW] * inv;
            o.y = zp[(c4 * 4 + 1) * HW] * inv;
            o.z = zp[(c4 * 4 + 2) * HW] * inv;
            o.w = zp[(c4 * 4 + 3) * HW] * inv;
            *(float4*)(zn + p * EDIM + c4 * 4) = o;
        }
    }
}

// ---------------- k_mfma: all 32768x8192 dists, per-pixel top-2 + flag -------
// Block: 2 waves x 32 pixels = 64 pixels; 512 blocks (2/CU). Per 16-code sub:
// 4 contiguous ds_read_b128 feed 12 MFMAs (2 pixel-sets).
// LDS layout per 64-code stage: subtile s (16 codes) x part {hi-k0,hi-k1,lo-k0,
// lo-k1} x 1024 B, fragment element for MFMA lane L at part_base + L*16.
// Layouts (HW-verified, guide §3): A[m=lane&15][k=quad*8+j],
// B[k=quad*8+j][n=lane&15], C/D row=(lane>>4)*4+reg, col=lane&15.
__global__ __launch_bounds__(128, 1) void k_mfma(const float* __restrict__ zn,
                                                 const short* __restrict__ eh,
                                                 const short* __restrict__ el,
                                                 const float* __restrict__ se_half,
                                                 unsigned* __restrict__ idx_arr,
                                                 unsigned* __restrict__ list,
                                                 unsigned* __restrict__ counter,
                                                 unsigned long long* __restrict__ packed) {
    __shared__ short es[NSTAGE * EDIM * 2];   // 16 KB: 4 subtiles x 4 parts x 512 shorts
    __shared__ float ses[NSTAGE];

    const int tid  = threadIdx.x;             // 0..127
    const int wave = tid >> 6, lane = tid & 63;
    const int quad = lane >> 4, col = lane & 15;
    const int p0   = blockIdx.x * 64 + wave * 32;   // wave's 32 pixels (2 sets)

    // A fragments: 2 sets of 16 pixels; fp32 zn -> bf16 hi + residual lo in regs
    bf16x8 ah[2][2], al[2][2];
    #pragma unroll
    for (int s = 0; s < 2; ++s) {
        const float* zr = zn + (p0 + s * 16 + col) * EDIM;
        #pragma unroll
        for (int kc = 0; kc < 2; ++kc) {
            float f[8];
            *(float4*)(f + 0) = *(const float4*)(zr + kc * 32 + quad * 8 + 0);
            *(float4*)(f + 4) = *(const float4*)(zr + kc * 32 + quad * 8 + 4);
            #pragma unroll
            for (int i = 0; i < 8; ++i) {
                ah[s][kc][i] = f2bf_bits(f[i]);
                al[s][kc][i] = f2bf_bits(f[i] - bf_hi_f(f[i]));
            }
        }
    }

    float b1[2][4], b2[2][4]; int i1[2][4];
    #pragma unroll
    for (int s = 0; s < 2; ++s)
        #pragma unroll
        for (int r = 0; r < 4; ++r) { b1[s][r] = 3.0e38f; b2[s][r] = 3.0e38f; i1[s][r] = 0; }

    for (int nb = 0; nb < NE / NSTAGE; ++nb) {
        const int n0 = nb * NSTAGE;
        // ---- stage 64 codes in fragment order: 1024 16B slots / 128 thr -----
        #pragma unroll
        for (int it = 0; it < 8; ++it) {
            const int slot = it * 128 + tid;
            const int c    = slot & 63;        // code within stage
            const int r    = slot >> 6;        // 0..15
            const int hilo = r >> 3;           // 0 = hi, 1 = lo
            const int o    = r & 7;            // 16B chunk within 128B code row
            const short* src = (hilo ? el : eh) + (n0 + c) * EDIM + o * 8;
            // dst fragment slot: subtile c>>4, part hilo*2+(o>>2), lane (o&3)*16+(c&15)
            const int dstv = (((c >> 4) * 4 + hilo * 2 + (o >> 2)) * 64
                              + (o & 3) * 16 + (c & 15)) * 8;   // in shorts
            *(int4*)(es + dstv) = *(const int4*)src;            // granule-distinct
        }
        if (tid < NSTAGE) ses[tid] = se_half[n0 + tid];
        __syncthreads();

        #pragma unroll
        for (int sub = 0; sub < NSTAGE / 16; ++sub) {
            const short* base = es + sub * 4 * 512;
            const bf16x8 bh0 = *(const bf16x8*)(base + 0 * 512 + lane * 8);  // contiguous
            const bf16x8 bh1 = *(const bf16x8*)(base + 1 * 512 + lane * 8);
            const bf16x8 bl0 = *(const bf16x8*)(base + 2 * 512 + lane * 8);
            const bf16x8 bl1 = *(const bf16x8*)(base + 3 * 512 + lane * 8);
            const float sse = ses[sub * 16 + col];
            const int nglob = n0 + sub * 16 + col;
            #pragma unroll
            for (int s = 0; s < 2; ++s) {
                f32x4 acc  = {0.f, 0.f, 0.f, 0.f};   // hi*hi
                f32x4 acc2 = {0.f, 0.f, 0.f, 0.f};   // cross terms
                acc  = __builtin_amdgcn_mfma_f32_16x16x32_bf16(ah[s][0], bh0, acc,  0, 0, 0);
                acc  = __builtin_amdgcn_mfma_f32_16x16x32_bf16(ah[s][1], bh1, acc,  0, 0, 0);
                acc2 = __builtin_amdgcn_mfma_f32_16x16x32_bf16(ah[s][0], bl0, acc2, 0, 0, 0);
                acc2 = __builtin_amdgcn_mfma_f32_16x16x32_bf16(ah[s][1], bl1, acc2, 0, 0, 0);
                acc2 = __builtin_amdgcn_mfma_f32_16x16x32_bf16(al[s][0], bh0, acc2, 0, 0, 0);
                acc2 = __builtin_amdgcn_mfma_f32_16x16x32_bf16(al[s][1], bh1, acc2, 0, 0, 0);
                #pragma unroll
                for (int r = 0; r < 4; ++r) {
                    const float dist = sse - acc[r] - acc2[r];
                    b2[s][r] = fminf(b2[s][r], fmaxf(b1[s][r], dist));  // new 2nd-best
                    const bool t = dist < b1[s][r];        // strict <, n ascending
                    b1[s][r] = fminf(b1[s][r], dist);
                    i1[s][r] = t ? nglob : i1[s][r];
                }
            }
        }
        __syncthreads();
    }

    // merge top-2 across the 16 col-lanes (xor 1,2,4,8 stays inside quad group)
    #pragma unroll
    for (int m = 1; m <= 8; m <<= 1) {
        #pragma unroll
        for (int s = 0; s < 2; ++s)
            #pragma unroll
            for (int r = 0; r < 4; ++r) {
                const float ob1 = __shfl_xor(b1[s][r], m, 64);
                const int   oi1 = __shfl_xor(i1[s][r], m, 64);
                const float ob2 = __shfl_xor(b2[s][r], m, 64);
                const bool take = (ob1 < b1[s][r]) || (ob1 == b1[s][r] && oi1 < i1[s][r]);
                b2[s][r] = fminf(fminf(b2[s][r], ob2), fmaxf(b1[s][r], ob1));
                b1[s][r] = take ? ob1 : b1[s][r];
                i1[s][r] = take ? oi1 : i1[s][r];
            }
    }
    if (col == 0) {
        #pragma unroll
        for (int s = 0; s < 2; ++s)
            #pragma unroll
            for (int r = 0; r < 4; ++r) {
                const int p = p0 + s * 16 + quad * 4 + r;   // C/D row = quad*4 + r
                const bool fl = (b2[s][r] - b1[s][r] < MARGIN);
                idx_arr[p] = (unsigned)i1[s][r] | (fl ? 0x80000000u : 0u);
                if (fl) {                       // near-tie: exact fp32 recheck
                    packed[p] = ~0ull;          // init argmin key for recheck
                    const unsigned pos = atomicAdd(counter, 1u);
                    if (pos < NPIX) list[pos] = p;
                }
            }
    }
}

// ---------------- recheck: exact fp32 argmin for flagged pixels --------------
// item = (flagged pixel, 512-code chunk); 4096 waves grid-stride. zn read at
// wave-uniform address -> s_load (SGPR-resident pixel vector).
__global__ __launch_bounds__(256) void k_recheck(const float* __restrict__ zn,
                                                 const float* __restrict__ e_norm,
                                                 const float* __restrict__ se_half,
                                                 const unsigned* __restrict__ list,
                                                 const unsigned* __restrict__ counter,
                                                 unsigned long long* __restrict__ packed) {
    const int lane  = threadIdx.x & 63;
    const int wglob = (blockIdx.x * 256 + threadIdx.x) >> 6;
    const int nwav  = (gridDim.x * 256) >> 6;
    int cnt = (int)*counter; if (cnt > NPIX) cnt = NPIX;
    const int nitems = cnt * 16;

    for (int item = wglob; item < nitems; item += nwav) {
        const int p     = (int)list[item >> 4];
        const int chunk = item & 15;
        const float4* zp4 = (const float4*)(zn + p * EDIM);   // uniform -> s_load
        const float4* e4  = (const float4*)e_norm;
        float best = 3.0e38f; int bidx = 0;
        #pragma unroll 1
        for (int j = 0; j < 8; j += 2) {                      // lane codes, ILP 2
            const int n0 = chunk * 512 + j * 64 + lane;
            const int n1 = n0 + 64;
            float a0 = 0.f, a1 = 0.f;
            #pragma unroll
            for (int c4 = 0; c4 < 16; ++c4) {
                const float4 zv = zp4[c4];
                const float4 e0 = e4[n0 * 16 + c4];
                const float4 e1 = e4[n1 * 16 + c4];
                a0 = fmaf(zv.w, e0.w, fmaf(zv.z, e0.z, fmaf(zv.y, e0.y, fmaf(zv.x, e0.x, a0))));
                a1 = fmaf(zv.w, e1.w, fmaf(zv.z, e1.z, fmaf(zv.y, e1.y, fmaf(zv.x, e1.x, a1))));
            }
            const float d0 = se_half[n0] - a0;
            const float d1 = se_half[n1] - a1;
            if (d0 < best) { best = d0; bidx = n0; }          // strict <, ascending
            if (d1 < best) { best = d1; bidx = n1; }
        }
        #pragma unroll
        for (int m = 1; m <= 32; m <<= 1) {                   // wave first-min
            const float ob = __shfl_xor(best, m, 64);
            const int   oi = __shfl_xor(bidx, m, 64);
            if (ob < best || (ob == best && oi < bidx)) { best = ob; bidx = oi; }
        }
        if (lane == 0) {
            const unsigned long long key =
                ((unsigned long long)order_u32(best) << 32) | (unsigned)bidx;
            atomicMin(&packed[p], key);
        }
    }
}

// ---------------- finalize: write indices + gather z_q (flag-aware) ----------
__global__ __launch_bounds__(256) void k_finalize(const unsigned* __restrict__ idx_arr,
                                                  const unsigned long long* __restrict__ packed,
                                                  const float* __restrict__ e_norm,
                                                  float* __restrict__ out) {
    const int p = blockIdx.x * 256 + threadIdx.x;
    const unsigned v = idx_arr[p];
    const int bidx = (v & 0x80000000u) ? (int)(packed[p] & 0xFFFFFFFFull)
                                       : (int)v;
    out[NPIX * EDIM + p] = (float)bidx;
    const int b = p >> 12, hw = p & (HW - 1);
    float* op = out + b * (EDIM * HW) + hw;
    const float* ep = e_norm + bidx * EDIM;
    #pragma unroll
    for (int c = 0; c < EDIM; ++c) op[c * HW] = ep[c];   // coalesced per c
}

extern "C" void kernel_launch(void* const* d_in, const int* in_sizes, int n_in,
                              void* d_out, int out_size, void* d_ws, size_t ws_size,
                              hipStream_t stream) {
    const float* z   = (const float*)d_in[0];
    const float* emb = (const float*)d_in[1];
    float* out = (float*)d_out;

    // workspace layout (~12.6 MB)
    float* e_norm  = (float*)d_ws;                       // 2 MB
    float* se_half = e_norm + NE * EDIM;                 // 32 KB
    short* eh = (short*)(se_half + NE);                  // 1 MB
    short* el = eh + NE * EDIM;                          // 1 MB
    float* zn = (float*)(el + NE * EDIM);                // 8 MB
    unsigned* idx_arr = (unsigned*)(zn + NPIX * EDIM);   // 128 KB
    unsigned* list    = idx_arr + NPIX;                  // 128 KB
    unsigned* counter = list + NPIX;                     // 4 B (+pad)
    unsigned long long* packed = (unsigned long long*)(counter + 64); // 256 KB

    hipMemsetAsync(counter, 0, sizeof(unsigned), stream);
    k_prep<<<NE / 4 + NPIX / 256, 256, 0, stream>>>(emb, z, e_norm, se_half, eh, el, zn);
    k_mfma<<<NPIX / 64, 128, 0, stream>>>(zn, eh, el, se_half,
                                          idx_arr, list, counter, packed);
    k_recheck<<<1024, 256, 0, stream>>>(zn, e_norm, se_half, list, counter, packed);
    k_finalize<<<NPIX / 256, 256, 0, stream>>>(idx_arr, packed, e_norm, out);
}

// Round 9
// 403.128 us; speedup vs baseline: 1.0686x; 1.0686x over previous
//
#include <hip/hip_runtime.h>
#include <hip/hip_bf16.h>

// VectorQuantizer: z [8,64,64,64] fp32 (BCHW), embedding [8192,64] fp32.
// Outputs (concat): z_q [8,64,64,64] fp32 (BCHW), indices [32768] as fp32.
//
// R9: R8's conflict-free fragment-order LDS + 2-pixel-set B-reuse kept, but
// occupancy restored via split-K x2 (each block scans half the codebook):
// 1024 blocks x 2 waves = 8 waves/CU (R8: 4 waves/CU, latency-bound at 266us,
// MfmaUtil 15.8%). Per-CU budget: MFMA 49.7us (limit), LDS-read 41us, VALU 28us.
// Exact merge of the 2 per-pixel partials preserves np argmin tie semantics.

#define NPIX 32768
#define NE   8192
#define EDIM 64
#define HW   4096
#define NSTAGE 64          // codes per LDS stage (4 subtiles of 16)
#define KSPLIT 2
#define CPS  (NE / KSPLIT) // 4096 codes per split
#define MARGIN 2.0e-4f

typedef short bf16x8 __attribute__((ext_vector_type(8)));
typedef float f32x4  __attribute__((ext_vector_type(4)));

__device__ __forceinline__ short f2bf_bits(float x) {
    __hip_bfloat16 h = __float2bfloat16(x);
    short s; __builtin_memcpy(&s, &h, 2); return s;
}
__device__ __forceinline__ float bf_hi_f(float x) {
    return __bfloat162float(__float2bfloat16(x));
}
// map float to unsigned with same total order
__device__ __forceinline__ unsigned int order_u32(float f) {
    unsigned int s = __float_as_uint(f);
    return (s & 0x80000000u) ? ~s : (s | 0x80000000u);
}

// ---------------- prep (fused): codebook part + pixel part -------------------
__global__ __launch_bounds__(256) void k_prep(const float* __restrict__ emb,
                                              const float* __restrict__ z,
                                              float* __restrict__ e_norm,
                                              float* __restrict__ se_half,
                                              short* __restrict__ eh,
                                              short* __restrict__ el,
                                              float* __restrict__ zn) {
    if (blockIdx.x < NE / 4) {
        // --- codebook: 1 code per wave ---
        const int wave = threadIdx.x >> 6;
        const int lane = threadIdx.x & 63;       // = channel
        const int n = blockIdx.x * 4 + wave;
        float v = emb[n * EDIM + lane];
        float ss = v * v;
        #pragma unroll
        for (int off = 32; off; off >>= 1) ss += __shfl_xor(ss, off, 64);
        const float inv = 1.0f / fmaxf(sqrtf(ss), 1e-12f);
        const float en = v * inv;
        e_norm[n * EDIM + lane] = en;
        const float hf = bf_hi_f(en);
        eh[n * EDIM + lane] = f2bf_bits(en);
        el[n * EDIM + lane] = f2bf_bits(en - hf);
        float s2 = en * en;
        #pragma unroll
        for (int off = 32; off; off >>= 1) s2 += __shfl_xor(s2, off, 64);
        if (lane == 0) se_half[n] = 0.5f * s2;
    } else {
        // --- pixels: normalize -> zn fp32 row-major [p][c] ---
        const int p = (blockIdx.x - NE / 4) * 256 + threadIdx.x;
        const int b = p >> 12, hw = p & (HW - 1);
        const float* zp = z + b * (EDIM * HW) + hw;
        float ss = 0.0f;
        for (int c = 0; c < EDIM; ++c) { const float v = zp[c * HW]; ss = fmaf(v, v, ss); }
        const float inv = 1.0f / fmaxf(sqrtf(ss), 1e-12f);
        for (int c4 = 0; c4 < 16; ++c4) {
            float4 o;
            o.x = zp[(c4 * 4 + 0) * HW] * inv;
            o.y = zp[(c4 * 4 + 1) * HW] * inv;
            o.z = zp[(c4 * 4 + 2) * HW] * inv;
            o.w = zp[(c4 * 4 + 3) * HW] * inv;
            *(float4*)(zn + p * EDIM + c4 * 4) = o;
        }
    }
}

// ---------------- k_mfma: split-K partial top-2 per pixel --------------------
// Block: 2 waves x 32 pixels = 64 pixels, one codebook half (blockIdx.y).
// 1024 blocks -> 4 blocks/CU (8 waves). Per 16-code subtile: 4 contiguous
// ds_read_b128 feed 12 MFMAs (2 pixel-sets, 3 independent 2-deep chains).
// LDS per 64-code stage: subtile x part {hi-k0,hi-k1,lo-k0,lo-k1} x 1 KB,
// fragment element for MFMA lane L at part_base + L*16 (conflict-free, R8: 0).
// Layouts (HW-verified): A[m=lane&15][k=quad*8+j], B[k=quad*8+j][n=lane&15],
// C/D row=(lane>>4)*4+reg, col=lane&15.
__global__ __launch_bounds__(128, 1) void k_mfma(const float* __restrict__ zn,
                                                 const short* __restrict__ eh,
                                                 const short* __restrict__ el,
                                                 const float* __restrict__ se_half,
                                                 float2* __restrict__ pv,   // [g][p] {b1,b2}
                                                 unsigned* __restrict__ pi) // [g][p] i1
{
    __shared__ short es[NSTAGE * EDIM * 2];   // 16 KB
    __shared__ float ses[NSTAGE];

    const int tid  = threadIdx.x;             // 0..127
    const int wave = tid >> 6, lane = tid & 63;
    const int quad = lane >> 4, col = lane & 15;
    const int p0   = blockIdx.x * 64 + wave * 32;   // wave's 32 pixels (2 sets)
    const int g    = blockIdx.y;                    // codebook half
    const int kbase = g * CPS;

    // A fragments: 2 sets of 16 pixels; fp32 zn -> bf16 hi + residual lo
    bf16x8 ah[2][2], al[2][2];
    #pragma unroll
    for (int s = 0; s < 2; ++s) {
        const float* zr = zn + (p0 + s * 16 + col) * EDIM;
        #pragma unroll
        for (int kc = 0; kc < 2; ++kc) {
            float f[8];
            *(float4*)(f + 0) = *(const float4*)(zr + kc * 32 + quad * 8 + 0);
            *(float4*)(f + 4) = *(const float4*)(zr + kc * 32 + quad * 8 + 4);
            #pragma unroll
            for (int i = 0; i < 8; ++i) {
                ah[s][kc][i] = f2bf_bits(f[i]);
                al[s][kc][i] = f2bf_bits(f[i] - bf_hi_f(f[i]));
            }
        }
    }

    float b1[2][4], b2[2][4]; int i1[2][4];
    #pragma unroll
    for (int s = 0; s < 2; ++s)
        #pragma unroll
        for (int r = 0; r < 4; ++r) { b1[s][r] = 3.0e38f; b2[s][r] = 3.0e38f; i1[s][r] = 0; }

    for (int nb = 0; nb < CPS / NSTAGE; ++nb) {
        const int n0 = kbase + nb * NSTAGE;
        // ---- stage 64 codes in fragment order: 1024 16B slots / 128 thr -----
        #pragma unroll
        for (int it = 0; it < 8; ++it) {
            const int slot = it * 128 + tid;
            const int c    = slot & 63;        // code within stage
            const int r    = slot >> 6;        // 0..15
            const int hilo = r >> 3;           // 0 = hi, 1 = lo
            const int o    = r & 7;            // 16B chunk within 128B code row
            const short* src = (hilo ? el : eh) + (n0 + c) * EDIM + o * 8;
            const int dstv = (((c >> 4) * 4 + hilo * 2 + (o >> 2)) * 64
                              + (o & 3) * 16 + (c & 15)) * 8;   // in shorts
            *(int4*)(es + dstv) = *(const int4*)src;            // granule-distinct
        }
        if (tid < NSTAGE) ses[tid] = se_half[n0 + tid];
        __syncthreads();

        #pragma unroll
        for (int sub = 0; sub < NSTAGE / 16; ++sub) {
            const short* base = es + sub * 4 * 512;
            const bf16x8 bh0 = *(const bf16x8*)(base + 0 * 512 + lane * 8);
            const bf16x8 bh1 = *(const bf16x8*)(base + 1 * 512 + lane * 8);
            const bf16x8 bl0 = *(const bf16x8*)(base + 2 * 512 + lane * 8);
            const bf16x8 bl1 = *(const bf16x8*)(base + 3 * 512 + lane * 8);
            const float sse = ses[sub * 16 + col];
            const int nglob = n0 + sub * 16 + col;
            #pragma unroll
            for (int s = 0; s < 2; ++s) {
                // 3 independent 2-deep MFMA chains
                f32x4 aa = {0.f, 0.f, 0.f, 0.f};   // hi*hi
                f32x4 ab = {0.f, 0.f, 0.f, 0.f};   // hi*lo
                f32x4 ac = {0.f, 0.f, 0.f, 0.f};   // lo*hi
                aa = __builtin_amdgcn_mfma_f32_16x16x32_bf16(ah[s][0], bh0, aa, 0, 0, 0);
                ab = __builtin_amdgcn_mfma_f32_16x16x32_bf16(ah[s][0], bl0, ab, 0, 0, 0);
                ac = __builtin_amdgcn_mfma_f32_16x16x32_bf16(al[s][0], bh0, ac, 0, 0, 0);
                aa = __builtin_amdgcn_mfma_f32_16x16x32_bf16(ah[s][1], bh1, aa, 0, 0, 0);
                ab = __builtin_amdgcn_mfma_f32_16x16x32_bf16(ah[s][1], bl1, ab, 0, 0, 0);
                ac = __builtin_amdgcn_mfma_f32_16x16x32_bf16(al[s][1], bh1, ac, 0, 0, 0);
                #pragma unroll
                for (int r = 0; r < 4; ++r) {
                    const float dist = ((sse - aa[r]) - ab[r]) - ac[r];
                    b2[s][r] = fminf(b2[s][r], fmaxf(b1[s][r], dist));  // new 2nd-best
                    const bool t = dist < b1[s][r];        // strict <, n ascending
                    b1[s][r] = fminf(b1[s][r], dist);
                    i1[s][r] = t ? nglob : i1[s][r];
                }
            }
        }
        __syncthreads();
    }

    // merge top-2 across the 16 col-lanes (xor 1,2,4,8 stays inside quad group)
    #pragma unroll
    for (int m = 1; m <= 8; m <<= 1) {
        #pragma unroll
        for (int s = 0; s < 2; ++s)
            #pragma unroll
            for (int r = 0; r < 4; ++r) {
                const float ob1 = __shfl_xor(b1[s][r], m, 64);
                const int   oi1 = __shfl_xor(i1[s][r], m, 64);
                const float ob2 = __shfl_xor(b2[s][r], m, 64);
                const bool take = (ob1 < b1[s][r]) || (ob1 == b1[s][r] && oi1 < i1[s][r]);
                b2[s][r] = fminf(fminf(b2[s][r], ob2), fmaxf(b1[s][r], ob1));
                b1[s][r] = take ? ob1 : b1[s][r];
                i1[s][r] = take ? oi1 : i1[s][r];
            }
    }
    if (col == 0) {
        #pragma unroll
        for (int s = 0; s < 2; ++s)
            #pragma unroll
            for (int r = 0; r < 4; ++r) {
                const int p = p0 + s * 16 + quad * 4 + r;   // C/D row = quad*4 + r
                pv[g * NPIX + p] = make_float2(b1[s][r], b2[s][r]);
                pi[g * NPIX + p] = (unsigned)i1[s][r];
            }
    }
}

// ---------------- merge: combine the 2 split-K partials, flag near-ties ------
__global__ __launch_bounds__(256) void k_merge(const float2* __restrict__ pv,
                                               const unsigned* __restrict__ pi,
                                               unsigned* __restrict__ idx_arr,
                                               unsigned* __restrict__ list,
                                               unsigned* __restrict__ counter,
                                               unsigned long long* __restrict__ packed) {
    const int p = blockIdx.x * 256 + threadIdx.x;
    const float2 va = pv[p];            // group 0 (codes 0..4095)
    const float2 vb = pv[NPIX + p];     // group 1 (codes 4096..8191)
    const unsigned ia = pi[p], ib = pi[NPIX + p];
    // group 0 wins exact ties (lower indices) -> strict <
    const bool tb = vb.x < va.x;
    const float b1 = tb ? vb.x : va.x;
    const unsigned i1 = tb ? ib : ia;
    const float b2 = fminf(fminf(va.y, vb.y), fmaxf(va.x, vb.x));
    const bool fl = (b2 - b1 < MARGIN);
    idx_arr[p] = i1 | (fl ? 0x80000000u : 0u);
    if (fl) {
        packed[p] = ~0ull;
        const unsigned pos = atomicAdd(counter, 1u);
        if (pos < NPIX) list[pos] = p;
    }
}

// ---------------- recheck: exact fp32 argmin for flagged pixels --------------
__global__ __launch_bounds__(256) void k_recheck(const float* __restrict__ zn,
                                                 const float* __restrict__ e_norm,
                                                 const float* __restrict__ se_half,
                                                 const unsigned* __restrict__ list,
                                                 const unsigned* __restrict__ counter,
                                                 unsigned long long* __restrict__ packed) {
    const int lane  = threadIdx.x & 63;
    const int wglob = (blockIdx.x * 256 + threadIdx.x) >> 6;
    const int nwav  = (gridDim.x * 256) >> 6;
    int cnt = (int)*counter; if (cnt > NPIX) cnt = NPIX;
    const int nitems = cnt * 16;

    for (int item = wglob; item < nitems; item += nwav) {
        const int p     = (int)list[item >> 4];
        const int chunk = item & 15;
        const float4* zp4 = (const float4*)(zn + p * EDIM);   // uniform -> s_load
        const float4* e4  = (const float4*)e_norm;
        float best = 3.0e38f; int bidx = 0;
        #pragma unroll 1
        for (int j = 0; j < 8; j += 2) {                      // lane codes, ILP 2
            const int n0 = chunk * 512 + j * 64 + lane;
            const int n1 = n0 + 64;
            float a0 = 0.f, a1 = 0.f;
            #pragma unroll
            for (int c4 = 0; c4 < 16; ++c4) {
                const float4 zv = zp4[c4];
                const float4 e0 = e4[n0 * 16 + c4];
                const float4 e1 = e4[n1 * 16 + c4];
                a0 = fmaf(zv.w, e0.w, fmaf(zv.z, e0.z, fmaf(zv.y, e0.y, fmaf(zv.x, e0.x, a0))));
                a1 = fmaf(zv.w, e1.w, fmaf(zv.z, e1.z, fmaf(zv.y, e1.y, fmaf(zv.x, e1.x, a1))));
            }
            const float d0 = se_half[n0] - a0;
            const float d1 = se_half[n1] - a1;
            if (d0 < best) { best = d0; bidx = n0; }          // strict <, ascending
            if (d1 < best) { best = d1; bidx = n1; }
        }
        #pragma unroll
        for (int m = 1; m <= 32; m <<= 1) {                   // wave first-min
            const float ob = __shfl_xor(best, m, 64);
            const int   oi = __shfl_xor(bidx, m, 64);
            if (ob < best || (ob == best && oi < bidx)) { best = ob; bidx = oi; }
        }
        if (lane == 0) {
            const unsigned long long key =
                ((unsigned long long)order_u32(best) << 32) | (unsigned)bidx;
            atomicMin(&packed[p], key);
        }
    }
}

// ---------------- finalize: write indices + gather z_q (flag-aware) ----------
__global__ __launch_bounds__(256) void k_finalize(const unsigned* __restrict__ idx_arr,
                                                  const unsigned long long* __restrict__ packed,
                                                  const float* __restrict__ e_norm,
                                                  float* __restrict__ out) {
    const int p = blockIdx.x * 256 + threadIdx.x;
    const unsigned v = idx_arr[p];
    const int bidx = (v & 0x80000000u) ? (int)(packed[p] & 0xFFFFFFFFull)
                                       : (int)v;
    out[NPIX * EDIM + p] = (float)bidx;
    const int b = p >> 12, hw = p & (HW - 1);
    float* op = out + b * (EDIM * HW) + hw;
    const float* ep = e_norm + bidx * EDIM;
    #pragma unroll
    for (int c = 0; c < EDIM; ++c) op[c * HW] = ep[c];   // coalesced per c
}

extern "C" void kernel_launch(void* const* d_in, const int* in_sizes, int n_in,
                              void* d_out, int out_size, void* d_ws, size_t ws_size,
                              hipStream_t stream) {
    const float* z   = (const float*)d_in[0];
    const float* emb = (const float*)d_in[1];
    float* out = (float*)d_out;

    // workspace layout (~13.4 MB)
    float* e_norm  = (float*)d_ws;                       // 2 MB
    float* se_half = e_norm + NE * EDIM;                 // 32 KB
    short* eh = (short*)(se_half + NE);                  // 1 MB
    short* el = eh + NE * EDIM;                          // 1 MB
    float* zn = (float*)(el + NE * EDIM);                // 8 MB
    unsigned* idx_arr = (unsigned*)(zn + NPIX * EDIM);   // 128 KB
    unsigned* list    = idx_arr + NPIX;                  // 128 KB
    unsigned* counter = list + NPIX;                     // 4 B (+pad)
    unsigned long long* packed = (unsigned long long*)(counter + 64); // 256 KB
    float2*   pv = (float2*)(packed + NPIX);             // 512 KB
    unsigned* pi = (unsigned*)(pv + KSPLIT * NPIX);      // 256 KB

    hipMemsetAsync(counter, 0, sizeof(unsigned), stream);
    k_prep<<<NE / 4 + NPIX / 256, 256, 0, stream>>>(emb, z, e_norm, se_half, eh, el, zn);
    k_mfma<<<dim3(NPIX / 64, KSPLIT), 128, 0, stream>>>(zn, eh, el, se_half, pv, pi);
    k_merge<<<NPIX / 256, 256, 0, stream>>>(pv, pi, idx_arr, list, counter, packed);
    k_recheck<<<1024, 256, 0, stream>>>(zn, e_norm, se_half, list, counter, packed);
    k_finalize<<<NPIX / 256, 256, 0, stream>>>(idx_arr, packed, e_norm, out);
}

// Round 10
// 390.524 us; speedup vs baseline: 1.1031x; 1.0323x over previous
//
#include <hip/hip_runtime.h>
#include <hip/hip_bf16.h>

// VectorQuantizer: z [8,64,64,64] fp32 (BCHW), embedding [8192,64] fp32.
// Outputs (concat): z_q [8,64,64,64] fp32 (BCHW), indices [32768] as fp32.
//
// R10: k_mfma was grid-limited (R9: 8 waves/CU peak, Occupancy 19.5%,
// VALUBusy 36%) and epilogue-heavy (8 VALU/dist -> 109us/CU vs MFMA 50us).
//  - KSPLIT 2->4: 2048 blocks x 2 waves = 16 waves/CU (LDS 8x16.9KB fits)
//  - epilogue 6 ops/dist: 2 MFMA chains + v_med3_f32 for 2nd-best update
//  - counter memset folded into k_prep

#define NPIX 32768
#define NE   8192
#define EDIM 64
#define HW   4096
#define NSTAGE 64          // codes per LDS stage (4 subtiles of 16)
#define KSPLIT 4
#define CPS  (NE / KSPLIT) // 2048 codes per split
#define MARGIN 2.0e-4f

typedef short bf16x8 __attribute__((ext_vector_type(8)));
typedef float f32x4  __attribute__((ext_vector_type(4)));

__device__ __forceinline__ short f2bf_bits(float x) {
    __hip_bfloat16 h = __float2bfloat16(x);
    short s; __builtin_memcpy(&s, &h, 2); return s;
}
__device__ __forceinline__ float bf_hi_f(float x) {
    return __bfloat162float(__float2bfloat16(x));
}
// map float to unsigned with same total order
__device__ __forceinline__ unsigned int order_u32(float f) {
    unsigned int s = __float_as_uint(f);
    return (s & 0x80000000u) ? ~s : (s | 0x80000000u);
}

// ---------------- prep (fused): codebook part + pixel part -------------------
__global__ __launch_bounds__(256) void k_prep(const float* __restrict__ emb,
                                              const float* __restrict__ z,
                                              float* __restrict__ e_norm,
                                              float* __restrict__ se_half,
                                              short* __restrict__ eh,
                                              short* __restrict__ el,
                                              float* __restrict__ zn,
                                              unsigned* __restrict__ counter) {
    if (blockIdx.x == 0 && threadIdx.x == 0) *counter = 0u;   // replaces memset
    if (blockIdx.x < NE / 4) {
        // --- codebook: 1 code per wave ---
        const int wave = threadIdx.x >> 6;
        const int lane = threadIdx.x & 63;       // = channel
        const int n = blockIdx.x * 4 + wave;
        float v = emb[n * EDIM + lane];
        float ss = v * v;
        #pragma unroll
        for (int off = 32; off; off >>= 1) ss += __shfl_xor(ss, off, 64);
        const float inv = 1.0f / fmaxf(sqrtf(ss), 1e-12f);
        const float en = v * inv;
        e_norm[n * EDIM + lane] = en;
        const float hf = bf_hi_f(en);
        eh[n * EDIM + lane] = f2bf_bits(en);
        el[n * EDIM + lane] = f2bf_bits(en - hf);
        float s2 = en * en;
        #pragma unroll
        for (int off = 32; off; off >>= 1) s2 += __shfl_xor(s2, off, 64);
        if (lane == 0) se_half[n] = 0.5f * s2;
    } else {
        // --- pixels: normalize -> zn fp32 row-major [p][c] ---
        const int p = (blockIdx.x - NE / 4) * 256 + threadIdx.x;
        const int b = p >> 12, hw = p & (HW - 1);
        const float* zp = z + b * (EDIM * HW) + hw;
        float ss = 0.0f;
        for (int c = 0; c < EDIM; ++c) { const float v = zp[c * HW]; ss = fmaf(v, v, ss); }
        const float inv = 1.0f / fmaxf(sqrtf(ss), 1e-12f);
        for (int c4 = 0; c4 < 16; ++c4) {
            float4 o;
            o.x = zp[(c4 * 4 + 0) * HW] * inv;
            o.y = zp[(c4 * 4 + 1) * HW] * inv;
            o.z = zp[(c4 * 4 + 2) * HW] * inv;
            o.w = zp[(c4 * 4 + 3) * HW] * inv;
            *(float4*)(zn + p * EDIM + c4 * 4) = o;
        }
    }
}

// ---------------- k_mfma: split-K partial top-2 per pixel --------------------
// Block: 2 waves x 32 pixels = 64 pixels, one codebook quarter (blockIdx.y).
// 2048 blocks -> 8 blocks/CU = 16 waves/CU. Per 16-code subtile: 4 contiguous
// ds_read_b128 feed 12 MFMAs (2 pixel-sets, 2 chains). Epilogue 6 VALU/dist
// (dist 2, med3 1, cmp/min/cndmask 3).
// LDS per 64-code stage: subtile x part {hi-k0,hi-k1,lo-k0,lo-k1} x 1 KB,
// fragment element for MFMA lane L at part_base + L*16 (conflict-free, R8: 0).
// Layouts (HW-verified): A[m=lane&15][k=quad*8+j], B[k=quad*8+j][n=lane&15],
// C/D row=(lane>>4)*4+reg, col=lane&15.
__global__ __launch_bounds__(128, 1) void k_mfma(const float* __restrict__ zn,
                                                 const short* __restrict__ eh,
                                                 const short* __restrict__ el,
                                                 const float* __restrict__ se_half,
                                                 float2* __restrict__ pv,   // [g][p] {b1,b2}
                                                 unsigned* __restrict__ pi) // [g][p] i1
{
    __shared__ short es[NSTAGE * EDIM * 2];   // 16 KB
    __shared__ float ses[NSTAGE];

    const int tid  = threadIdx.x;             // 0..127
    const int wave = tid >> 6, lane = tid & 63;
    const int quad = lane >> 4, col = lane & 15;
    const int p0   = blockIdx.x * 64 + wave * 32;   // wave's 32 pixels (2 sets)
    const int g    = blockIdx.y;                    // codebook quarter
    const int kbase = g * CPS;

    // A fragments: 2 sets of 16 pixels; fp32 zn -> bf16 hi + residual lo
    bf16x8 ah[2][2], al[2][2];
    #pragma unroll
    for (int s = 0; s < 2; ++s) {
        const float* zr = zn + (p0 + s * 16 + col) * EDIM;
        #pragma unroll
        for (int kc = 0; kc < 2; ++kc) {
            float f[8];
            *(float4*)(f + 0) = *(const float4*)(zr + kc * 32 + quad * 8 + 0);
            *(float4*)(f + 4) = *(const float4*)(zr + kc * 32 + quad * 8 + 4);
            #pragma unroll
            for (int i = 0; i < 8; ++i) {
                ah[s][kc][i] = f2bf_bits(f[i]);
                al[s][kc][i] = f2bf_bits(f[i] - bf_hi_f(f[i]));
            }
        }
    }

    float b1[2][4], b2[2][4]; int i1[2][4];
    #pragma unroll
    for (int s = 0; s < 2; ++s)
        #pragma unroll
        for (int r = 0; r < 4; ++r) { b1[s][r] = 3.0e38f; b2[s][r] = 3.0e38f; i1[s][r] = 0; }

    for (int nb = 0; nb < CPS / NSTAGE; ++nb) {
        const int n0 = kbase + nb * NSTAGE;
        // ---- stage 64 codes in fragment order: 1024 16B slots / 128 thr -----
        #pragma unroll
        for (int it = 0; it < 8; ++it) {
            const int slot = it * 128 + tid;
            const int c    = slot & 63;        // code within stage
            const int r    = slot >> 6;        // 0..15
            const int hilo = r >> 3;           // 0 = hi, 1 = lo
            const int o    = r & 7;            // 16B chunk within 128B code row
            const short* src = (hilo ? el : eh) + (n0 + c) * EDIM + o * 8;
            const int dstv = (((c >> 4) * 4 + hilo * 2 + (o >> 2)) * 64
                              + (o & 3) * 16 + (c & 15)) * 8;   // in shorts
            *(int4*)(es + dstv) = *(const int4*)src;            // granule-distinct
        }
        if (tid < NSTAGE) ses[tid] = se_half[n0 + tid];
        __syncthreads();

        #pragma unroll
        for (int sub = 0; sub < NSTAGE / 16; ++sub) {
            const short* base = es + sub * 4 * 512;
            const bf16x8 bh0 = *(const bf16x8*)(base + 0 * 512 + lane * 8);
            const bf16x8 bh1 = *(const bf16x8*)(base + 1 * 512 + lane * 8);
            const bf16x8 bl0 = *(const bf16x8*)(base + 2 * 512 + lane * 8);
            const bf16x8 bl1 = *(const bf16x8*)(base + 3 * 512 + lane * 8);
            const float sse = ses[sub * 16 + col];
            const int nglob = n0 + sub * 16 + col;
            #pragma unroll
            for (int s = 0; s < 2; ++s) {
                // 2 MFMA chains: hi*hi and cross terms
                f32x4 acc  = {0.f, 0.f, 0.f, 0.f};
                f32x4 acc2 = {0.f, 0.f, 0.f, 0.f};
                acc  = __builtin_amdgcn_mfma_f32_16x16x32_bf16(ah[s][0], bh0, acc,  0, 0, 0);
                acc2 = __builtin_amdgcn_mfma_f32_16x16x32_bf16(ah[s][0], bl0, acc2, 0, 0, 0);
                acc  = __builtin_amdgcn_mfma_f32_16x16x32_bf16(ah[s][1], bh1, acc,  0, 0, 0);
                acc2 = __builtin_amdgcn_mfma_f32_16x16x32_bf16(al[s][0], bh0, acc2, 0, 0, 0);
                acc2 = __builtin_amdgcn_mfma_f32_16x16x32_bf16(ah[s][1], bl1, acc2, 0, 0, 0);
                acc2 = __builtin_amdgcn_mfma_f32_16x16x32_bf16(al[s][1], bh1, acc2, 0, 0, 0);
                #pragma unroll
                for (int r = 0; r < 4; ++r) {
                    const float dist = (sse - acc[r]) - acc2[r];
                    // b1 <= b2 invariant -> med3(b1,b2,dist) == new 2nd-best (1 instr)
                    b2[s][r] = __builtin_amdgcn_fmed3f(b1[s][r], b2[s][r], dist);
                    const bool t = dist < b1[s][r];        // strict <, n ascending
                    b1[s][r] = fminf(b1[s][r], dist);
                    i1[s][r] = t ? nglob : i1[s][r];
                }
            }
        }
        __syncthreads();
    }

    // merge top-2 across the 16 col-lanes (xor 1,2,4,8 stays inside quad group)
    #pragma unroll
    for (int m = 1; m <= 8; m <<= 1) {
        #pragma unroll
        for (int s = 0; s < 2; ++s)
            #pragma unroll
            for (int r = 0; r < 4; ++r) {
                const float ob1 = __shfl_xor(b1[s][r], m, 64);
                const int   oi1 = __shfl_xor(i1[s][r], m, 64);
                const float ob2 = __shfl_xor(b2[s][r], m, 64);
                const bool take = (ob1 < b1[s][r]) || (ob1 == b1[s][r] && oi1 < i1[s][r]);
                b2[s][r] = fminf(__builtin_amdgcn_fmed3f(b1[s][r], b2[s][r], ob1), ob2);
                b1[s][r] = take ? ob1 : b1[s][r];
                i1[s][r] = take ? oi1 : i1[s][r];
            }
    }
    if (col == 0) {
        #pragma unroll
        for (int s = 0; s < 2; ++s)
            #pragma unroll
            for (int r = 0; r < 4; ++r) {
                const int p = p0 + s * 16 + quad * 4 + r;   // C/D row = quad*4 + r
                pv[g * NPIX + p] = make_float2(b1[s][r], b2[s][r]);
                pi[g * NPIX + p] = (unsigned)i1[s][r];
            }
    }
}

// ---------------- merge: combine KSPLIT partials, flag near-ties -------------
__global__ __launch_bounds__(256) void k_merge(const float2* __restrict__ pv,
                                               const unsigned* __restrict__ pi,
                                               unsigned* __restrict__ idx_arr,
                                               unsigned* __restrict__ list,
                                               unsigned* __restrict__ counter,
                                               unsigned long long* __restrict__ packed) {
    const int p = blockIdx.x * 256 + threadIdx.x;
    float2 v[KSPLIT]; unsigned ix[KSPLIT];
    #pragma unroll
    for (int gg = 0; gg < KSPLIT; ++gg) { v[gg] = pv[gg * NPIX + p]; ix[gg] = pi[gg * NPIX + p]; }
    // ascending group order + strict < == np first-occurrence tie semantics
    float b1 = v[0].x; unsigned i1 = ix[0]; int win = 0;
    #pragma unroll
    for (int gg = 1; gg < KSPLIT; ++gg)
        if (v[gg].x < b1) { b1 = v[gg].x; i1 = ix[gg]; win = gg; }
    float b2 = 3.0e38f;
    #pragma unroll
    for (int gg = 0; gg < KSPLIT; ++gg) {
        b2 = fminf(b2, v[gg].y);
        if (gg != win) b2 = fminf(b2, v[gg].x);
    }
    const bool fl = (b2 - b1 < MARGIN);
    idx_arr[p] = i1 | (fl ? 0x80000000u : 0u);
    if (fl) {
        packed[p] = ~0ull;
        const unsigned pos = atomicAdd(counter, 1u);
        if (pos < NPIX) list[pos] = p;
    }
}

// ---------------- recheck: exact fp32 argmin for flagged pixels --------------
__global__ __launch_bounds__(256) void k_recheck(const float* __restrict__ zn,
                                                 const float* __restrict__ e_norm,
                                                 const float* __restrict__ se_half,
                                                 const unsigned* __restrict__ list,
                                                 const unsigned* __restrict__ counter,
                                                 unsigned long long* __restrict__ packed) {
    const int lane  = threadIdx.x & 63;
    const int wglob = (blockIdx.x * 256 + threadIdx.x) >> 6;
    const int nwav  = (gridDim.x * 256) >> 6;
    int cnt = (int)*counter; if (cnt > NPIX) cnt = NPIX;
    const int nitems = cnt * 16;

    for (int item = wglob; item < nitems; item += nwav) {
        const int p     = (int)list[item >> 4];
        const int chunk = item & 15;
        const float4* zp4 = (const float4*)(zn + p * EDIM);   // uniform -> s_load
        const float4* e4  = (const float4*)e_norm;
        float best = 3.0e38f; int bidx = 0;
        #pragma unroll 1
        for (int j = 0; j < 8; j += 2) {                      // lane codes, ILP 2
            const int n0 = chunk * 512 + j * 64 + lane;
            const int n1 = n0 + 64;
            float a0 = 0.f, a1 = 0.f;
            #pragma unroll
            for (int c4 = 0; c4 < 16; ++c4) {
                const float4 zv = zp4[c4];
                const float4 e0 = e4[n0 * 16 + c4];
                const float4 e1 = e4[n1 * 16 + c4];
                a0 = fmaf(zv.w, e0.w, fmaf(zv.z, e0.z, fmaf(zv.y, e0.y, fmaf(zv.x, e0.x, a0))));
                a1 = fmaf(zv.w, e1.w, fmaf(zv.z, e1.z, fmaf(zv.y, e1.y, fmaf(zv.x, e1.x, a1))));
            }
            const float d0 = se_half[n0] - a0;
            const float d1 = se_half[n1] - a1;
            if (d0 < best) { best = d0; bidx = n0; }          // strict <, ascending
            if (d1 < best) { best = d1; bidx = n1; }
        }
        #pragma unroll
        for (int m = 1; m <= 32; m <<= 1) {                   // wave first-min
            const float ob = __shfl_xor(best, m, 64);
            const int   oi = __shfl_xor(bidx, m, 64);
            if (ob < best || (ob == best && oi < bidx)) { best = ob; bidx = oi; }
        }
        if (lane == 0) {
            const unsigned long long key =
                ((unsigned long long)order_u32(best) << 32) | (unsigned)bidx;
            atomicMin(&packed[p], key);
        }
    }
}

// ---------------- finalize: write indices + gather z_q (flag-aware) ----------
__global__ __launch_bounds__(256) void k_finalize(const unsigned* __restrict__ idx_arr,
                                                  const unsigned long long* __restrict__ packed,
                                                  const float* __restrict__ e_norm,
                                                  float* __restrict__ out) {
    const int p = blockIdx.x * 256 + threadIdx.x;
    const unsigned v = idx_arr[p];
    const int bidx = (v & 0x80000000u) ? (int)(packed[p] & 0xFFFFFFFFull)
                                       : (int)v;
    out[NPIX * EDIM + p] = (float)bidx;
    const int b = p >> 12, hw = p & (HW - 1);
    float* op = out + b * (EDIM * HW) + hw;
    const float* ep = e_norm + bidx * EDIM;
    #pragma unroll
    for (int c = 0; c < EDIM; ++c) op[c * HW] = ep[c];   // coalesced per c
}

extern "C" void kernel_launch(void* const* d_in, const int* in_sizes, int n_in,
                              void* d_out, int out_size, void* d_ws, size_t ws_size,
                              hipStream_t stream) {
    const float* z   = (const float*)d_in[0];
    const float* emb = (const float*)d_in[1];
    float* out = (float*)d_out;

    // workspace layout (~14.2 MB)
    float* e_norm  = (float*)d_ws;                       // 2 MB
    float* se_half = e_norm + NE * EDIM;                 // 32 KB
    short* eh = (short*)(se_half + NE);                  // 1 MB
    short* el = eh + NE * EDIM;                          // 1 MB
    float* zn = (float*)(el + NE * EDIM);                // 8 MB
    unsigned* idx_arr = (unsigned*)(zn + NPIX * EDIM);   // 128 KB
    unsigned* list    = idx_arr + NPIX;                  // 128 KB
    unsigned* counter = list + NPIX;                     // 4 B (+pad)
    unsigned long long* packed = (unsigned long long*)(counter + 64); // 256 KB
    float2*   pv = (float2*)(packed + NPIX);             // 1 MB
    unsigned* pi = (unsigned*)(pv + KSPLIT * NPIX);      // 512 KB

    k_prep<<<NE / 4 + NPIX / 256, 256, 0, stream>>>(emb, z, e_norm, se_half,
                                                    eh, el, zn, counter);
    k_mfma<<<dim3(NPIX / 64, KSPLIT), 128, 0, stream>>>(zn, eh, el, se_half, pv, pi);
    k_merge<<<NPIX / 256, 256, 0, stream>>>(pv, pi, idx_arr, list, counter, packed);
    k_recheck<<<1024, 256, 0, stream>>>(zn, e_norm, se_half, list, counter, packed);
    k_finalize<<<NPIX / 256, 256, 0, stream>>>(idx_arr, packed, e_norm, out);
}

// Round 11
// 382.003 us; speedup vs baseline: 1.1277x; 1.0223x over previous
//
#include <hip/hip_runtime.h>
#include <hip/hip_bf16.h>

// VectorQuantizer: z [8,64,64,64] fp32 (BCHW), embedding [8192,64] fp32.
// Outputs (concat): z_q [8,64,64,64] fp32 (BCHW), indices [32768] as fp32.
//
// R11: k_mfma residency was stuck at ~3 blocks/CU (~6 waves) regardless of
// grid (R9 19.5%, R10 17.6% occupancy) -> latency-bound at 226us vs ~80-100us
// overlap floor (VALU 72 / LDS 61 / MFMA 43 us per CU).
//  - 256-thr blocks (4 waves): ~12 waves/CU at the same block cap; 128 pixels
//    share each staged tile (staging per pixel halved)
//  - KSPLIT 8: grid 256x8=2048 blocks, never grid-limited
//  - reg-level stage prefetch: next stage's global loads issue before compute,
//    vmcnt drain happens ~64 subtiles later, not at the barrier

#define NPIX 32768
#define NE   8192
#define EDIM 64
#define HW   4096
#define NSTAGE 64          // codes per LDS stage (4 subtiles of 16)
#define KSPLIT 8
#define CPS  (NE / KSPLIT) // 1024 codes per split
#define MARGIN 2.0e-4f

typedef short bf16x8 __attribute__((ext_vector_type(8)));
typedef float f32x4  __attribute__((ext_vector_type(4)));

__device__ __forceinline__ short f2bf_bits(float x) {
    __hip_bfloat16 h = __float2bfloat16(x);
    short s; __builtin_memcpy(&s, &h, 2); return s;
}
__device__ __forceinline__ float bf_hi_f(float x) {
    return __bfloat162float(__float2bfloat16(x));
}
// map float to unsigned with same total order
__device__ __forceinline__ unsigned int order_u32(float f) {
    unsigned int s = __float_as_uint(f);
    return (s & 0x80000000u) ? ~s : (s | 0x80000000u);
}

// ---------------- prep (fused): codebook part + pixel part -------------------
__global__ __launch_bounds__(256) void k_prep(const float* __restrict__ emb,
                                              const float* __restrict__ z,
                                              float* __restrict__ e_norm,
                                              float* __restrict__ se_half,
                                              short* __restrict__ eh,
                                              short* __restrict__ el,
                                              float* __restrict__ zn,
                                              unsigned* __restrict__ counter) {
    if (blockIdx.x == 0 && threadIdx.x == 0) *counter = 0u;   // replaces memset
    if (blockIdx.x < NE / 4) {
        // --- codebook: 1 code per wave ---
        const int wave = threadIdx.x >> 6;
        const int lane = threadIdx.x & 63;       // = channel
        const int n = blockIdx.x * 4 + wave;
        float v = emb[n * EDIM + lane];
        float ss = v * v;
        #pragma unroll
        for (int off = 32; off; off >>= 1) ss += __shfl_xor(ss, off, 64);
        const float inv = 1.0f / fmaxf(sqrtf(ss), 1e-12f);
        const float en = v * inv;
        e_norm[n * EDIM + lane] = en;
        const float hf = bf_hi_f(en);
        eh[n * EDIM + lane] = f2bf_bits(en);
        el[n * EDIM + lane] = f2bf_bits(en - hf);
        float s2 = en * en;
        #pragma unroll
        for (int off = 32; off; off >>= 1) s2 += __shfl_xor(s2, off, 64);
        if (lane == 0) se_half[n] = 0.5f * s2;
    } else {
        // --- pixels: normalize -> zn fp32 row-major [p][c] ---
        const int p = (blockIdx.x - NE / 4) * 256 + threadIdx.x;
        const int b = p >> 12, hw = p & (HW - 1);
        const float* zp = z + b * (EDIM * HW) + hw;
        float ss = 0.0f;
        for (int c = 0; c < EDIM; ++c) { const float v = zp[c * HW]; ss = fmaf(v, v, ss); }
        const float inv = 1.0f / fmaxf(sqrtf(ss), 1e-12f);
        for (int c4 = 0; c4 < 16; ++c4) {
            float4 o;
            o.x = zp[(c4 * 4 + 0) * HW] * inv;
            o.y = zp[(c4 * 4 + 1) * HW] * inv;
            o.z = zp[(c4 * 4 + 2) * HW] * inv;
            o.w = zp[(c4 * 4 + 3) * HW] * inv;
            *(float4*)(zn + p * EDIM + c4 * 4) = o;
        }
    }
}

// ---------------- k_mfma: split-K partial top-2 per pixel --------------------
// Block: 4 waves x 32 pixels = 128 pixels, one codebook eighth (blockIdx.y).
// 2048 blocks. Per 16-code subtile: 4 contiguous ds_read_b128 feed 12 MFMAs
// (2 pixel-sets, 2 chains); epilogue 6 VALU/dist-reg. Stage loop is a reg-dbuf
// pipeline: global loads for stage nb+1 in flight during compute of nb.
// LDS per 64-code stage: subtile x part {hi-k0,hi-k1,lo-k0,lo-k1} x 1 KB,
// fragment element for MFMA lane L at part_base + L*16 (conflict-free, R8: 0).
// Layouts (HW-verified): A[m=lane&15][k=quad*8+j], B[k=quad*8+j][n=lane&15],
// C/D row=(lane>>4)*4+reg, col=lane&15.
__global__ __launch_bounds__(256, 1) void k_mfma(const float* __restrict__ zn,
                                                 const short* __restrict__ eh,
                                                 const short* __restrict__ el,
                                                 const float* __restrict__ se_half,
                                                 float2* __restrict__ pv,   // [g][p] {b1,b2}
                                                 unsigned* __restrict__ pi) // [g][p] i1
{
    __shared__ short es[NSTAGE * EDIM * 2];   // 16 KB
    __shared__ float ses[NSTAGE];

    const int tid  = threadIdx.x;             // 0..255
    const int wave = tid >> 6, lane = tid & 63;
    const int quad = lane >> 4, col = lane & 15;
    const int p0   = blockIdx.x * 128 + wave * 32;  // wave's 32 pixels (2 sets)
    const int g    = blockIdx.y;                    // codebook eighth
    const int kbase = g * CPS;

    // staging geometry: 1024 16B slots / 256 thr = 4 per thread
    const int s_c     = tid & 63;             // code within stage
    const int base_r  = tid >> 6;             // 0..3 -> chunks base_r + 4*it

    // A fragments: 2 sets of 16 pixels; fp32 zn -> bf16 hi + residual lo
    bf16x8 ah[2][2], al[2][2];
    #pragma unroll
    for (int s = 0; s < 2; ++s) {
        const float* zr = zn + (p0 + s * 16 + col) * EDIM;
        #pragma unroll
        for (int kc = 0; kc < 2; ++kc) {
            float f[8];
            *(float4*)(f + 0) = *(const float4*)(zr + kc * 32 + quad * 8 + 0);
            *(float4*)(f + 4) = *(const float4*)(zr + kc * 32 + quad * 8 + 4);
            #pragma unroll
            for (int i = 0; i < 8; ++i) {
                ah[s][kc][i] = f2bf_bits(f[i]);
                al[s][kc][i] = f2bf_bits(f[i] - bf_hi_f(f[i]));
            }
        }
    }

    float b1[2][4], b2[2][4]; int i1[2][4];
    #pragma unroll
    for (int s = 0; s < 2; ++s)
        #pragma unroll
        for (int r = 0; r < 4; ++r) { b1[s][r] = 3.0e38f; b2[s][r] = 3.0e38f; i1[s][r] = 0; }

    // ---- prefetch stage 0 into registers ----
    int4 pre[4]; float pse;
    {
        const int n0 = kbase;
        #pragma unroll
        for (int it = 0; it < 4; ++it) {
            const int r = base_r + it * 4;
            const int hilo = r >> 3, o = r & 7;
            pre[it] = *(const int4*)((hilo ? el : eh) + (n0 + s_c) * EDIM + o * 8);
        }
        pse = (tid < NSTAGE) ? se_half[n0 + tid] : 0.0f;
    }

    for (int nb = 0; nb < CPS / NSTAGE; ++nb) {
        const int n0 = kbase + nb * NSTAGE;
        __syncthreads();   // previous stage's compute done; LDS reusable
        // ---- write prefetched stage to LDS (fragment order) ----
        #pragma unroll
        for (int it = 0; it < 4; ++it) {
            const int r = base_r + it * 4;
            const int hilo = r >> 3, o = r & 7;
            const int dstv = (((s_c >> 4) * 4 + hilo * 2 + (o >> 2)) * 64
                              + (o & 3) * 16 + (s_c & 15)) * 8;   // in shorts
            *(int4*)(es + dstv) = pre[it];
        }
        if (tid < NSTAGE) ses[tid] = pse;
        // ---- issue next stage's global loads (in flight during compute) ----
        if (nb + 1 < CPS / NSTAGE) {
            const int n1 = n0 + NSTAGE;
            #pragma unroll
            for (int it = 0; it < 4; ++it) {
                const int r = base_r + it * 4;
                const int hilo = r >> 3, o = r & 7;
                pre[it] = *(const int4*)((hilo ? el : eh) + (n1 + s_c) * EDIM + o * 8);
            }
            pse = (tid < NSTAGE) ? se_half[n1 + tid] : 0.0f;
        }
        __syncthreads();   // stage visible

        #pragma unroll
        for (int sub = 0; sub < NSTAGE / 16; ++sub) {
            const short* base = es + sub * 4 * 512;
            const bf16x8 bh0 = *(const bf16x8*)(base + 0 * 512 + lane * 8);
            const bf16x8 bh1 = *(const bf16x8*)(base + 1 * 512 + lane * 8);
            const bf16x8 bl0 = *(const bf16x8*)(base + 2 * 512 + lane * 8);
            const bf16x8 bl1 = *(const bf16x8*)(base + 3 * 512 + lane * 8);
            const float sse = ses[sub * 16 + col];
            const int nglob = n0 + sub * 16 + col;
            #pragma unroll
            for (int s = 0; s < 2; ++s) {
                // 2 MFMA chains: hi*hi and cross terms
                f32x4 acc  = {0.f, 0.f, 0.f, 0.f};
                f32x4 acc2 = {0.f, 0.f, 0.f, 0.f};
                acc  = __builtin_amdgcn_mfma_f32_16x16x32_bf16(ah[s][0], bh0, acc,  0, 0, 0);
                acc2 = __builtin_amdgcn_mfma_f32_16x16x32_bf16(ah[s][0], bl0, acc2, 0, 0, 0);
                acc  = __builtin_amdgcn_mfma_f32_16x16x32_bf16(ah[s][1], bh1, acc,  0, 0, 0);
                acc2 = __builtin_amdgcn_mfma_f32_16x16x32_bf16(al[s][0], bh0, acc2, 0, 0, 0);
                acc2 = __builtin_amdgcn_mfma_f32_16x16x32_bf16(ah[s][1], bl1, acc2, 0, 0, 0);
                acc2 = __builtin_amdgcn_mfma_f32_16x16x32_bf16(al[s][1], bh1, acc2, 0, 0, 0);
                #pragma unroll
                for (int r = 0; r < 4; ++r) {
                    const float dist = (sse - acc[r]) - acc2[r];
                    // b1 <= b2 invariant -> med3(b1,b2,dist) == new 2nd-best (1 instr)
                    b2[s][r] = __builtin_amdgcn_fmed3f(b1[s][r], b2[s][r], dist);
                    const bool t = dist < b1[s][r];        // strict <, n ascending
                    b1[s][r] = fminf(b1[s][r], dist);
                    i1[s][r] = t ? nglob : i1[s][r];
                }
            }
        }
    }

    // merge top-2 across the 16 col-lanes (xor 1,2,4,8 stays inside quad group)
    #pragma unroll
    for (int m = 1; m <= 8; m <<= 1) {
        #pragma unroll
        for (int s = 0; s < 2; ++s)
            #pragma unroll
            for (int r = 0; r < 4; ++r) {
                const float ob1 = __shfl_xor(b1[s][r], m, 64);
                const int   oi1 = __shfl_xor(i1[s][r], m, 64);
                const float ob2 = __shfl_xor(b2[s][r], m, 64);
                const bool take = (ob1 < b1[s][r]) || (ob1 == b1[s][r] && oi1 < i1[s][r]);
                b2[s][r] = fminf(__builtin_amdgcn_fmed3f(b1[s][r], b2[s][r], ob1), ob2);
                b1[s][r] = take ? ob1 : b1[s][r];
                i1[s][r] = take ? oi1 : i1[s][r];
            }
    }
    if (col == 0) {
        #pragma unroll
        for (int s = 0; s < 2; ++s)
            #pragma unroll
            for (int r = 0; r < 4; ++r) {
                const int p = p0 + s * 16 + quad * 4 + r;   // C/D row = quad*4 + r
                pv[g * NPIX + p] = make_float2(b1[s][r], b2[s][r]);
                pi[g * NPIX + p] = (unsigned)i1[s][r];
            }
    }
}

// ---------------- merge: combine KSPLIT partials, flag near-ties -------------
__global__ __launch_bounds__(256) void k_merge(const float2* __restrict__ pv,
                                               const unsigned* __restrict__ pi,
                                               unsigned* __restrict__ idx_arr,
                                               unsigned* __restrict__ list,
                                               unsigned* __restrict__ counter,
                                               unsigned long long* __restrict__ packed) {
    const int p = blockIdx.x * 256 + threadIdx.x;
    float2 v[KSPLIT]; unsigned ix[KSPLIT];
    #pragma unroll
    for (int gg = 0; gg < KSPLIT; ++gg) { v[gg] = pv[gg * NPIX + p]; ix[gg] = pi[gg * NPIX + p]; }
    // ascending group order + strict < == np first-occurrence tie semantics
    float b1 = v[0].x; unsigned i1 = ix[0]; int win = 0;
    #pragma unroll
    for (int gg = 1; gg < KSPLIT; ++gg)
        if (v[gg].x < b1) { b1 = v[gg].x; i1 = ix[gg]; win = gg; }
    float b2 = 3.0e38f;
    #pragma unroll
    for (int gg = 0; gg < KSPLIT; ++gg) {
        b2 = fminf(b2, v[gg].y);
        if (gg != win) b2 = fminf(b2, v[gg].x);
    }
    const bool fl = (b2 - b1 < MARGIN);
    idx_arr[p] = i1 | (fl ? 0x80000000u : 0u);
    if (fl) {
        packed[p] = ~0ull;
        const unsigned pos = atomicAdd(counter, 1u);
        if (pos < NPIX) list[pos] = p;
    }
}

// ---------------- recheck: exact fp32 argmin for flagged pixels --------------
__global__ __launch_bounds__(256) void k_recheck(const float* __restrict__ zn,
                                                 const float* __restrict__ e_norm,
                                                 const float* __restrict__ se_half,
                                                 const unsigned* __restrict__ list,
                                                 const unsigned* __restrict__ counter,
                                                 unsigned long long* __restrict__ packed) {
    const int lane  = threadIdx.x & 63;
    const int wglob = (blockIdx.x * 256 + threadIdx.x) >> 6;
    const int nwav  = (gridDim.x * 256) >> 6;
    int cnt = (int)*counter; if (cnt > NPIX) cnt = NPIX;
    const int nitems = cnt * 16;

    for (int item = wglob; item < nitems; item += nwav) {
        const int p     = (int)list[item >> 4];
        const int chunk = item & 15;
        const float4* zp4 = (const float4*)(zn + p * EDIM);   // uniform -> s_load
        const float4* e4  = (const float4*)e_norm;
        float best = 3.0e38f; int bidx = 0;
        #pragma unroll 1
        for (int j = 0; j < 8; j += 2) {                      // lane codes, ILP 2
            const int n0 = chunk * 512 + j * 64 + lane;
            const int n1 = n0 + 64;
            float a0 = 0.f, a1 = 0.f;
            #pragma unroll
            for (int c4 = 0; c4 < 16; ++c4) {
                const float4 zv = zp4[c4];
                const float4 e0 = e4[n0 * 16 + c4];
                const float4 e1 = e4[n1 * 16 + c4];
                a0 = fmaf(zv.w, e0.w, fmaf(zv.z, e0.z, fmaf(zv.y, e0.y, fmaf(zv.x, e0.x, a0))));
                a1 = fmaf(zv.w, e1.w, fmaf(zv.z, e1.z, fmaf(zv.y, e1.y, fmaf(zv.x, e1.x, a1))));
            }
            const float d0 = se_half[n0] - a0;
            const float d1 = se_half[n1] - a1;
            if (d0 < best) { best = d0; bidx = n0; }          // strict <, ascending
            if (d1 < best) { best = d1; bidx = n1; }
        }
        #pragma unroll
        for (int m = 1; m <= 32; m <<= 1) {                   // wave first-min
            const float ob = __shfl_xor(best, m, 64);
            const int   oi = __shfl_xor(bidx, m, 64);
            if (ob < best || (ob == best && oi < bidx)) { best = ob; bidx = oi; }
        }
        if (lane == 0) {
            const unsigned long long key =
                ((unsigned long long)order_u32(best) << 32) | (unsigned)bidx;
            atomicMin(&packed[p], key);
        }
    }
}

// ---------------- finalize: write indices + gather z_q (flag-aware) ----------
__global__ __launch_bounds__(256) void k_finalize(const unsigned* __restrict__ idx_arr,
                                                  const unsigned long long* __restrict__ packed,
                                                  const float* __restrict__ e_norm,
                                                  float* __restrict__ out) {
    const int p = blockIdx.x * 256 + threadIdx.x;
    const unsigned v = idx_arr[p];
    const int bidx = (v & 0x80000000u) ? (int)(packed[p] & 0xFFFFFFFFull)
                                       : (int)v;
    out[NPIX * EDIM + p] = (float)bidx;
    const int b = p >> 12, hw = p & (HW - 1);
    float* op = out + b * (EDIM * HW) + hw;
    const float* ep = e_norm + bidx * EDIM;
    #pragma unroll
    for (int c = 0; c < EDIM; ++c) op[c * HW] = ep[c];   // coalesced per c
}

extern "C" void kernel_launch(void* const* d_in, const int* in_sizes, int n_in,
                              void* d_out, int out_size, void* d_ws, size_t ws_size,
                              hipStream_t stream) {
    const float* z   = (const float*)d_in[0];
    const float* emb = (const float*)d_in[1];
    float* out = (float*)d_out;

    // workspace layout (~15.6 MB)
    float* e_norm  = (float*)d_ws;                       // 2 MB
    float* se_half = e_norm + NE * EDIM;                 // 32 KB
    short* eh = (short*)(se_half + NE);                  // 1 MB
    short* el = eh + NE * EDIM;                          // 1 MB
    float* zn = (float*)(el + NE * EDIM);                // 8 MB
    unsigned* idx_arr = (unsigned*)(zn + NPIX * EDIM);   // 128 KB
    unsigned* list    = idx_arr + NPIX;                  // 128 KB
    unsigned* counter = list + NPIX;                     // 4 B (+pad)
    unsigned long long* packed = (unsigned long long*)(counter + 64); // 256 KB
    float2*   pv = (float2*)(packed + NPIX);             // 2 MB
    unsigned* pi = (unsigned*)(pv + KSPLIT * NPIX);      // 1 MB

    k_prep<<<NE / 4 + NPIX / 256, 256, 0, stream>>>(emb, z, e_norm, se_half,
                                                    eh, el, zn, counter);
    k_mfma<<<dim3(NPIX / 128, KSPLIT), 256, 0, stream>>>(zn, eh, el, se_half, pv, pi);
    k_merge<<<NPIX / 256, 256, 0, stream>>>(pv, pi, idx_arr, list, counter, packed);
    k_recheck<<<1024, 256, 0, stream>>>(zn, e_norm, se_half, list, counter, packed);
    k_finalize<<<NPIX / 256, 256, 0, stream>>>(idx_arr, packed, e_norm, out);
}

// Round 12
// 234.081 us; speedup vs baseline: 1.8404x; 1.6319x over previous
//
#include <hip/hip_runtime.h>
#include <hip/hip_bf16.h>

// VectorQuantizer: z [8,64,64,64] fp32 (BCHW), embedding [8192,64] fp32.
// Outputs (concat): z_q [8,64,64,64] fp32 (BCHW), indices [32768] as fp32.
//
// R12: occupancy capped by unified VGPR+AGPR file (R9-R11 ~8 waves/CU; arch 108
// + acc ~64 = 172 -> 2 waves/SIMD). Changes:
//  - staging via global_load_lds (16B, registerless, async): k_prep pre-swizzles
//    the codebook into stage-fragment order (esw) so src AND dst are
//    uniform + lane*16 -> coalesced 1KB per instruction, no staging VGPRs,
//    LDS double-buffer, 1 barrier/stage
//  - k_recheck coalesced: 4 codes x 16 lanes per b128 (1KB contiguous),
//    intra-16-lane shfl reduce (R11 replay showed 25MB fetch from 4x line
//    amplification of lane-per-code gathers)
//  - k_finalize 4 threads/pixel (512 blocks)

#define NPIX 32768
#define NE   8192
#define EDIM 64
#define HW   4096
#define NSTAGE 64           // codes per LDS stage (4 subtiles of 16)
#define KSPLIT 8
#define CPS  (NE / KSPLIT)  // 1024 codes per split
#define NSTG (CPS / NSTAGE) // 16 stages per block
#define MARGIN 2.0e-4f

typedef short bf16x8 __attribute__((ext_vector_type(8)));
typedef float f32x4  __attribute__((ext_vector_type(4)));

__device__ __forceinline__ short f2bf_bits(float x) {
    __hip_bfloat16 h = __float2bfloat16(x);
    short s; __builtin_memcpy(&s, &h, 2); return s;
}
__device__ __forceinline__ float bf_hi_f(float x) {
    return __bfloat162float(__float2bfloat16(x));
}
// map float to unsigned with same total order
__device__ __forceinline__ unsigned int order_u32(float f) {
    unsigned int s = __float_as_uint(f);
    return (s & 0x80000000u) ? ~s : (s | 0x80000000u);
}
// async global->LDS, 16B/lane; HW writes lane i at lds_base + i*16 (wave-uniform base)
__device__ __forceinline__ void gload_lds16(const void* g, void* l) {
    __builtin_amdgcn_global_load_lds(
        (const __attribute__((address_space(1))) void*)g,
        (__attribute__((address_space(3))) void*)l, 16, 0, 0);
}

// ---------------- prep (fused): codebook (swizzled bf16 hi/lo) + pixels ------
// esw layout = exactly the k_mfma LDS stage image: per 64-code stage, 16 combos
// (sub[4] x {hi-k0,hi-k1,lo-k0,lo-k1}) x 1KB; within combo, MFMA-B fragment
// order: slot frag_lane = (o&3)*16 + code_col holds 8 channels (16B).
__global__ __launch_bounds__(256) void k_prep(const float* __restrict__ emb,
                                              const float* __restrict__ z,
                                              float* __restrict__ e_norm,
                                              float* __restrict__ se_half,
                                              short* __restrict__ esw,
                                              float* __restrict__ zn,
                                              unsigned* __restrict__ counter) {
    if (blockIdx.x == 0 && threadIdx.x == 0) *counter = 0u;
    if (blockIdx.x < NE / 4) {
        // --- codebook: 1 code per wave, lane = channel ---
        const int wave = threadIdx.x >> 6;
        const int lane = threadIdx.x & 63;
        const int n = blockIdx.x * 4 + wave;
        float v = emb[n * EDIM + lane];
        float ss = v * v;
        #pragma unroll
        for (int off = 32; off; off >>= 1) ss += __shfl_xor(ss, off, 64);
        const float inv = 1.0f / fmaxf(sqrtf(ss), 1e-12f);
        const float en = v * inv;
        e_norm[n * EDIM + lane] = en;
        const float hf = bf_hi_f(en);
        // swizzled write (c = lane)
        const int stage = n >> 6, cs = n & 63;
        const int sub = cs >> 4, colb = cs & 15;
        const int o = lane >> 3, j = lane & 7;
        const int slot = ((o & 3) * 16 + colb) * 8 + j;
        short* sbase = esw + stage * 8192 + (sub * 4 + (o >> 2)) * 512;
        sbase[slot] = f2bf_bits(en);                 // hi combos (+0,+1)
        sbase[2 * 512 + slot] = f2bf_bits(en - hf);  // lo combos (+2,+3)
        float s2 = en * en;
        #pragma unroll
        for (int off = 32; off; off >>= 1) s2 += __shfl_xor(s2, off, 64);
        if (lane == 0) se_half[n] = 0.5f * s2;
    } else {
        // --- pixels: normalize -> zn fp32 row-major [p][c] ---
        const int p = (blockIdx.x - NE / 4) * 256 + threadIdx.x;
        const int b = p >> 12, hw = p & (HW - 1);
        const float* zp = z + b * (EDIM * HW) + hw;
        float ss = 0.0f;
        for (int c = 0; c < EDIM; ++c) { const float v = zp[c * HW]; ss = fmaf(v, v, ss); }
        const float inv = 1.0f / fmaxf(sqrtf(ss), 1e-12f);
        for (int c4 = 0; c4 < 16; ++c4) {
            float4 o;
            o.x = zp[(c4 * 4 + 0) * HW] * inv;
            o.y = zp[(c4 * 4 + 1) * HW] * inv;
            o.z = zp[(c4 * 4 + 2) * HW] * inv;
            o.w = zp[(c4 * 4 + 3) * HW] * inv;
            *(float4*)(zn + p * EDIM + c4 * 4) = o;
        }
    }
}

// ---------------- k_mfma: split-K partial top-2 per pixel --------------------
// Block: 4 waves x 32 pixels = 128 pixels, one codebook eighth (blockIdx.y).
// Staging: each wave issues 4 global_load_lds (1KB each, combos wave*4..+3)
// for stage nb+1 into the other LDS buffer right after the barrier; loads fly
// during the whole compute phase; compiler's vmcnt-drain before the next
// barrier completes them. 1 barrier/stage, zero staging VGPRs.
// Layouts (HW-verified): A[m=lane&15][k=quad*8+j], B[k=quad*8+j][n=lane&15],
// C/D row=(lane>>4)*4+reg, col=lane&15.
__global__ __launch_bounds__(256, 1) void k_mfma(const float* __restrict__ zn,
                                                 const short* __restrict__ esw,
                                                 const float* __restrict__ se_half,
                                                 float2* __restrict__ pv,   // [g][p] {b1,b2}
                                                 unsigned* __restrict__ pi) // [g][p] i1
{
    __shared__ __align__(16) short es[2][NSTAGE * EDIM * 2];   // 2 x 16KB

    const int tid  = threadIdx.x;             // 0..255
    const int wave = tid >> 6, lane = tid & 63;
    const int quad = lane >> 4, col = lane & 15;
    const int p0   = blockIdx.x * 128 + wave * 32;  // wave's 32 pixels (2 sets)
    const int g    = blockIdx.y;                    // codebook eighth
    const int kbase = g * CPS;

    // A fragments: 2 sets of 16 pixels; fp32 zn -> bf16 hi + residual lo
    bf16x8 ah[2][2], al[2][2];
    #pragma unroll
    for (int s = 0; s < 2; ++s) {
        const float* zr = zn + (p0 + s * 16 + col) * EDIM;
        #pragma unroll
        for (int kc = 0; kc < 2; ++kc) {
            float f[8];
            *(float4*)(f + 0) = *(const float4*)(zr + kc * 32 + quad * 8 + 0);
            *(float4*)(f + 4) = *(const float4*)(zr + kc * 32 + quad * 8 + 4);
            #pragma unroll
            for (int i = 0; i < 8; ++i) {
                ah[s][kc][i] = f2bf_bits(f[i]);
                al[s][kc][i] = f2bf_bits(f[i] - bf_hi_f(f[i]));
            }
        }
    }

    float b1[2][4], b2[2][4]; int i1[2][4];
    #pragma unroll
    for (int s = 0; s < 2; ++s)
        #pragma unroll
        for (int r = 0; r < 4; ++r) { b1[s][r] = 3.0e38f; b2[s][r] = 3.0e38f; i1[s][r] = 0; }

    // this wave's staging window: src and dst are both uniform + lane*16
    const int combo0 = wave * 4;
    const char* gsrc0 = (const char*)esw + (size_t)kbase * 256
                        + combo0 * 1024 + lane * 16;
    // prologue: issue stage 0 -> buf 0
    #pragma unroll
    for (int it = 0; it < 4; ++it)
        gload_lds16(gsrc0 + it * 1024, (char*)&es[0][0] + (combo0 + it) * 1024);

    for (int nb = 0; nb < NSTG; ++nb) {
        const int cur = nb & 1;
        const int n0 = kbase + nb * NSTAGE;
        __syncthreads();   // compiler drains vmcnt first: buf[cur] complete,
                           // prior compute's ds_reads done -> buf[cur^1] reusable
        if (nb + 1 < NSTG) {
            const char* gsrc = gsrc0 + (size_t)(nb + 1) * (NSTAGE * 256);
            #pragma unroll
            for (int it = 0; it < 4; ++it)
                gload_lds16(gsrc + it * 1024,
                            (char*)&es[cur ^ 1][0] + (combo0 + it) * 1024);
        }
        // per-stage se prefetch (L2-resident, hidden under MFMA)
        float sse_r[4];
        #pragma unroll
        for (int sub = 0; sub < 4; ++sub) sse_r[sub] = se_half[n0 + sub * 16 + col];

        const short* esb = es[cur];
        #pragma unroll
        for (int sub = 0; sub < 4; ++sub) {
            const short* base = esb + sub * 2048;
            const bf16x8 bh0 = *(const bf16x8*)(base + 0 * 512 + lane * 8);
            const bf16x8 bh1 = *(const bf16x8*)(base + 1 * 512 + lane * 8);
            const bf16x8 bl0 = *(const bf16x8*)(base + 2 * 512 + lane * 8);
            const bf16x8 bl1 = *(const bf16x8*)(base + 3 * 512 + lane * 8);
            const float sse = sse_r[sub];
            const int nglob = n0 + sub * 16 + col;
            #pragma unroll
            for (int s = 0; s < 2; ++s) {
                f32x4 acc  = {0.f, 0.f, 0.f, 0.f};   // hi*hi
                f32x4 acc2 = {0.f, 0.f, 0.f, 0.f};   // cross terms
                acc  = __builtin_amdgcn_mfma_f32_16x16x32_bf16(ah[s][0], bh0, acc,  0, 0, 0);
                acc2 = __builtin_amdgcn_mfma_f32_16x16x32_bf16(ah[s][0], bl0, acc2, 0, 0, 0);
                acc  = __builtin_amdgcn_mfma_f32_16x16x32_bf16(ah[s][1], bh1, acc,  0, 0, 0);
                acc2 = __builtin_amdgcn_mfma_f32_16x16x32_bf16(al[s][0], bh0, acc2, 0, 0, 0);
                acc2 = __builtin_amdgcn_mfma_f32_16x16x32_bf16(ah[s][1], bl1, acc2, 0, 0, 0);
                acc2 = __builtin_amdgcn_mfma_f32_16x16x32_bf16(al[s][1], bh1, acc2, 0, 0, 0);
                #pragma unroll
                for (int r = 0; r < 4; ++r) {
                    const float dist = (sse - acc[r]) - acc2[r];
                    // b1 <= b2 invariant -> med3 == new 2nd-best (1 instr)
                    b2[s][r] = __builtin_amdgcn_fmed3f(b1[s][r], b2[s][r], dist);
                    const bool t = dist < b1[s][r];        // strict <, n ascending
                    b1[s][r] = fminf(b1[s][r], dist);
                    i1[s][r] = t ? nglob : i1[s][r];
                }
            }
        }
    }

    // merge top-2 across the 16 col-lanes (xor 1,2,4,8 stays inside quad group)
    #pragma unroll
    for (int m = 1; m <= 8; m <<= 1) {
        #pragma unroll
        for (int s = 0; s < 2; ++s)
            #pragma unroll
            for (int r = 0; r < 4; ++r) {
                const float ob1 = __shfl_xor(b1[s][r], m, 64);
                const int   oi1 = __shfl_xor(i1[s][r], m, 64);
                const float ob2 = __shfl_xor(b2[s][r], m, 64);
                const bool take = (ob1 < b1[s][r]) || (ob1 == b1[s][r] && oi1 < i1[s][r]);
                b2[s][r] = fminf(__builtin_amdgcn_fmed3f(b1[s][r], b2[s][r], ob1), ob2);
                b1[s][r] = take ? ob1 : b1[s][r];
                i1[s][r] = take ? oi1 : i1[s][r];
            }
    }
    if (col == 0) {
        #pragma unroll
        for (int s = 0; s < 2; ++s)
            #pragma unroll
            for (int r = 0; r < 4; ++r) {
                const int p = p0 + s * 16 + quad * 4 + r;   // C/D row = quad*4 + r
                pv[g * NPIX + p] = make_float2(b1[s][r], b2[s][r]);
                pi[g * NPIX + p] = (unsigned)i1[s][r];
            }
    }
}

// ---------------- merge: combine KSPLIT partials, flag near-ties -------------
__global__ __launch_bounds__(256) void k_merge(const float2* __restrict__ pv,
                                               const unsigned* __restrict__ pi,
                                               unsigned* __restrict__ idx_arr,
                                               unsigned* __restrict__ list,
                                               unsigned* __restrict__ counter,
                                               unsigned long long* __restrict__ packed) {
    const int p = blockIdx.x * 256 + threadIdx.x;
    float2 v[KSPLIT]; unsigned ix[KSPLIT];
    #pragma unroll
    for (int gg = 0; gg < KSPLIT; ++gg) { v[gg] = pv[gg * NPIX + p]; ix[gg] = pi[gg * NPIX + p]; }
    // ascending group order + strict < == np first-occurrence tie semantics
    float b1 = v[0].x; unsigned i1 = ix[0]; int win = 0;
    #pragma unroll
    for (int gg = 1; gg < KSPLIT; ++gg)
        if (v[gg].x < b1) { b1 = v[gg].x; i1 = ix[gg]; win = gg; }
    float b2 = 3.0e38f;
    #pragma unroll
    for (int gg = 0; gg < KSPLIT; ++gg) {
        b2 = fminf(b2, v[gg].y);
        if (gg != win) b2 = fminf(b2, v[gg].x);
    }
    const bool fl = (b2 - b1 < MARGIN);
    idx_arr[p] = i1 | (fl ? 0x80000000u : 0u);
    if (fl) {
        packed[p] = ~0ull;
        const unsigned pos = atomicAdd(counter, 1u);
        if (pos < NPIX) list[pos] = p;
    }
}

// ---------------- recheck: exact fp32 argmin for flagged pixels --------------
// item = (flagged pixel, 512-code chunk). Coalesced: 4 codes x 16 lanes per
// b128 (contiguous 1KB from L2-resident e_norm); dot reduced via 4 shfl_xor
// inside each 16-lane group.
__global__ __launch_bounds__(256) void k_recheck(const float* __restrict__ zn,
                                                 const float* __restrict__ e_norm,
                                                 const float* __restrict__ se_half,
                                                 const unsigned* __restrict__ list,
                                                 const unsigned* __restrict__ counter,
                                                 unsigned long long* __restrict__ packed) {
    const int lane  = threadIdx.x & 63;
    const int k     = lane >> 4;        // code-in-group 0..3
    const int m     = lane & 15;        // c4 index 0..15
    const int wglob = (blockIdx.x * 256 + threadIdx.x) >> 6;
    const int nwav  = (gridDim.x * 256) >> 6;
    int cnt = (int)*counter; if (cnt > NPIX) cnt = NPIX;
    const int nitems = cnt * 16;
    const float4* e4 = (const float4*)e_norm;

    for (int item = wglob; item < nitems; item += nwav) {
        const int p     = (int)list[item >> 4];
        const int chunk = item & 15;
        const float4 zv = *(const float4*)(zn + p * EDIM + m * 4);  // bcast/16 lanes
        float best = 3.0e38f; int bidx = 0;
        #pragma unroll 2
        for (int t = 0; t < 128; ++t) {                // 4 codes per iteration
            const int n = chunk * 512 + t * 4 + k;     // lane's code this iter
            const float4 ev = e4[n * 16 + m];          // lane-linear: 1KB contiguous
            float s = fmaf(zv.w, ev.w, fmaf(zv.z, ev.z,
                      fmaf(zv.y, ev.y, zv.x * ev.x)));
            s += __shfl_xor(s, 1, 64); s += __shfl_xor(s, 2, 64);
            s += __shfl_xor(s, 4, 64); s += __shfl_xor(s, 8, 64);
            const float d = se_half[n] - s;            // all 16 lanes same d
            if (d < best) { best = d; bidx = n; }      // lane's codes ascending
        }
        #pragma unroll
        for (int mm = 1; mm <= 32; mm <<= 1) {         // wave first-min
            const float ob = __shfl_xor(best, mm, 64);
            const int   oi = __shfl_xor(bidx, mm, 64);
            if (ob < best || (ob == best && oi < bidx)) { best = ob; bidx = oi; }
        }
        if (lane == 0) {
            const unsigned long long key =
                ((unsigned long long)order_u32(best) << 32) | (unsigned)bidx;
            atomicMin(&packed[p], key);
        }
    }
}

// ---------------- finalize: write indices + gather z_q (4 thr/pixel) ---------
__global__ __launch_bounds__(256) void k_finalize(const unsigned* __restrict__ idx_arr,
                                                  const unsigned long long* __restrict__ packed,
                                                  const float* __restrict__ e_norm,
                                                  float* __restrict__ out) {
    const int pl = threadIdx.x & 63;
    const int q  = threadIdx.x >> 6;                  // channel quarter 0..3
    const int p  = blockIdx.x * 64 + pl;
    const unsigned v = idx_arr[p];
    const int bidx = (v & 0x80000000u) ? (int)(packed[p] & 0xFFFFFFFFull)
                                       : (int)v;
    if (q == 0) out[NPIX * EDIM + p] = (float)bidx;
    const int b = p >> 12, hw = p & (HW - 1);
    float* op = out + b * (EDIM * HW) + hw;
    const float4* ep4 = (const float4*)(e_norm + bidx * EDIM + q * 16);
    #pragma unroll
    for (int j = 0; j < 4; ++j) {
        const float4 e = ep4[j];
        const int c = q * 16 + j * 4;
        op[(c + 0) * HW] = e.x; op[(c + 1) * HW] = e.y;   // coalesced per c
        op[(c + 2) * HW] = e.z; op[(c + 3) * HW] = e.w;
    }
}

extern "C" void kernel_launch(void* const* d_in, const int* in_sizes, int n_in,
                              void* d_out, int out_size, void* d_ws, size_t ws_size,
                              hipStream_t stream) {
    const float* z   = (const float*)d_in[0];
    const float* emb = (const float*)d_in[1];
    float* out = (float*)d_out;

    // workspace layout (~15.6 MB)
    float* e_norm  = (float*)d_ws;                       // 2 MB
    float* se_half = e_norm + NE * EDIM;                 // 32 KB
    short* esw = (short*)(se_half + NE);                 // 2 MB (swizzled hi+lo)
    float* zn = (float*)(esw + NE * EDIM * 2);           // 8 MB
    unsigned* idx_arr = (unsigned*)(zn + NPIX * EDIM);   // 128 KB
    unsigned* list    = idx_arr + NPIX;                  // 128 KB
    unsigned* counter = list + NPIX;                     // 4 B (+pad)
    unsigned long long* packed = (unsigned long long*)(counter + 64); // 256 KB
    float2*   pv = (float2*)(packed + NPIX);             // 2 MB
    unsigned* pi = (unsigned*)(pv + KSPLIT * NPIX);      // 1 MB

    k_prep<<<NE / 4 + NPIX / 256, 256, 0, stream>>>(emb, z, e_norm, se_half,
                                                    esw, zn, counter);
    k_mfma<<<dim3(NPIX / 128, KSPLIT), 256, 0, stream>>>(zn, esw, se_half, pv, pi);
    k_merge<<<NPIX / 256, 256, 0, stream>>>(pv, pi, idx_arr, list, counter, packed);
    k_recheck<<<1024, 256, 0, stream>>>(zn, e_norm, se_half, list, counter, packed);
    k_finalize<<<NPIX / 64, 256, 0, stream>>>(idx_arr, packed, e_norm, out);
}

// Round 13
// 213.170 us; speedup vs baseline: 2.0209x; 1.0981x over previous
//
#include <hip/hip_runtime.h>
#include <hip/hip_bf16.h>

// VectorQuantizer: z [8,64,64,64] fp32 (BCHW), embedding [8192,64] fp32.
// Outputs (concat): z_q [8,64,64,64] fp32 (BCHW), indices [32768] as fp32.
//
// R13: k_mfma hot-loop VALU diet (R12: VALUBusy 52.7% > MfmaUtil 29.7%).
// Single 6-deep MFMA chain per pixel-set, C seeded with {-sse} -> acc = -dist
// directly; top-2 tracked in max-space with 4 ops/reg (med3/max/cmp/cndmask).
// Removes 8 init movs + 16 dist-subs per subtile (~40% hot-loop VALU).
// Staging (R12, proven): global_load_lds 16B registerless from pre-swizzled
// codebook, LDS double-buffer, 1 barrier/stage, 0 bank conflicts.

#define NPIX 32768
#define NE   8192
#define EDIM 64
#define HW   4096
#define NSTAGE 64           // codes per LDS stage (4 subtiles of 16)
#define KSPLIT 8
#define CPS  (NE / KSPLIT)  // 1024 codes per split
#define NSTG (CPS / NSTAGE) // 16 stages per block
#define MARGIN 2.0e-4f

typedef short bf16x8 __attribute__((ext_vector_type(8)));
typedef float f32x4  __attribute__((ext_vector_type(4)));

__device__ __forceinline__ short f2bf_bits(float x) {
    __hip_bfloat16 h = __float2bfloat16(x);
    short s; __builtin_memcpy(&s, &h, 2); return s;
}
__device__ __forceinline__ float bf_hi_f(float x) {
    return __bfloat162float(__float2bfloat16(x));
}
// map float to unsigned with same total order
__device__ __forceinline__ unsigned int order_u32(float f) {
    unsigned int s = __float_as_uint(f);
    return (s & 0x80000000u) ? ~s : (s | 0x80000000u);
}
// async global->LDS, 16B/lane; HW writes lane i at lds_base + i*16 (wave-uniform base)
__device__ __forceinline__ void gload_lds16(const void* g, void* l) {
    __builtin_amdgcn_global_load_lds(
        (const __attribute__((address_space(1))) void*)g,
        (__attribute__((address_space(3))) void*)l, 16, 0, 0);
}

// ---------------- prep (fused): codebook (swizzled bf16 hi/lo) + pixels ------
// esw layout = exactly the k_mfma LDS stage image: per 64-code stage, 16 combos
// (sub[4] x {hi-k0,hi-k1,lo-k0,lo-k1}) x 1KB; within combo, MFMA-B fragment
// order: slot frag_lane = (o&3)*16 + code_col holds 8 channels (16B).
__global__ __launch_bounds__(256) void k_prep(const float* __restrict__ emb,
                                              const float* __restrict__ z,
                                              float* __restrict__ e_norm,
                                              float* __restrict__ se_half,
                                              short* __restrict__ esw,
                                              float* __restrict__ zn,
                                              unsigned* __restrict__ counter) {
    if (blockIdx.x == 0 && threadIdx.x == 0) *counter = 0u;
    if (blockIdx.x < NE / 4) {
        // --- codebook: 1 code per wave, lane = channel ---
        const int wave = threadIdx.x >> 6;
        const int lane = threadIdx.x & 63;
        const int n = blockIdx.x * 4 + wave;
        float v = emb[n * EDIM + lane];
        float ss = v * v;
        #pragma unroll
        for (int off = 32; off; off >>= 1) ss += __shfl_xor(ss, off, 64);
        const float inv = 1.0f / fmaxf(sqrtf(ss), 1e-12f);
        const float en = v * inv;
        e_norm[n * EDIM + lane] = en;
        const float hf = bf_hi_f(en);
        // swizzled write (c = lane)
        const int stage = n >> 6, cs = n & 63;
        const int sub = cs >> 4, colb = cs & 15;
        const int o = lane >> 3, j = lane & 7;
        const int slot = ((o & 3) * 16 + colb) * 8 + j;
        short* sbase = esw + stage * 8192 + (sub * 4 + (o >> 2)) * 512;
        sbase[slot] = f2bf_bits(en);                 // hi combos (+0,+1)
        sbase[2 * 512 + slot] = f2bf_bits(en - hf);  // lo combos (+2,+3)
        float s2 = en * en;
        #pragma unroll
        for (int off = 32; off; off >>= 1) s2 += __shfl_xor(s2, off, 64);
        if (lane == 0) se_half[n] = 0.5f * s2;
    } else {
        // --- pixels: normalize -> zn fp32 row-major [p][c] ---
        const int p = (blockIdx.x - NE / 4) * 256 + threadIdx.x;
        const int b = p >> 12, hw = p & (HW - 1);
        const float* zp = z + b * (EDIM * HW) + hw;
        float ss = 0.0f;
        for (int c = 0; c < EDIM; ++c) { const float v = zp[c * HW]; ss = fmaf(v, v, ss); }
        const float inv = 1.0f / fmaxf(sqrtf(ss), 1e-12f);
        for (int c4 = 0; c4 < 16; ++c4) {
            float4 o;
            o.x = zp[(c4 * 4 + 0) * HW] * inv;
            o.y = zp[(c4 * 4 + 1) * HW] * inv;
            o.z = zp[(c4 * 4 + 2) * HW] * inv;
            o.w = zp[(c4 * 4 + 3) * HW] * inv;
            *(float4*)(zn + p * EDIM + c4 * 4) = o;
        }
    }
}

// ---------------- k_mfma: split-K partial top-2 per pixel (max-space) --------
// Block: 4 waves x 32 pixels = 128 pixels, one codebook eighth (blockIdx.y).
// v = acc[r] = dot - sse = -dist; argmin dist == argmax v; strict > keeps the
// earliest code on ties (codes ascend). Layouts (HW-verified):
// A[m=lane&15][k=quad*8+j], B[k=quad*8+j][n=lane&15], C/D row=(lane>>4)*4+reg,
// col=lane&15.
__global__ __launch_bounds__(256, 1) void k_mfma(const float* __restrict__ zn,
                                                 const short* __restrict__ esw,
                                                 const float* __restrict__ se_half,
                                                 float2* __restrict__ pv,   // [g][p] {b1,b2} (max-space)
                                                 unsigned* __restrict__ pi) // [g][p] i1
{
    __shared__ __align__(16) short es[2][NSTAGE * EDIM * 2];   // 2 x 16KB

    const int tid  = threadIdx.x;             // 0..255
    const int wave = tid >> 6, lane = tid & 63;
    const int quad = lane >> 4, col = lane & 15;
    const int p0   = blockIdx.x * 128 + wave * 32;  // wave's 32 pixels (2 sets)
    const int g    = blockIdx.y;                    // codebook eighth
    const int kbase = g * CPS;

    // A fragments: 2 sets of 16 pixels; fp32 zn -> bf16 hi + residual lo
    bf16x8 ah[2][2], al[2][2];
    #pragma unroll
    for (int s = 0; s < 2; ++s) {
        const float* zr = zn + (p0 + s * 16 + col) * EDIM;
        #pragma unroll
        for (int kc = 0; kc < 2; ++kc) {
            float f[8];
            *(float4*)(f + 0) = *(const float4*)(zr + kc * 32 + quad * 8 + 0);
            *(float4*)(f + 4) = *(const float4*)(zr + kc * 32 + quad * 8 + 4);
            #pragma unroll
            for (int i = 0; i < 8; ++i) {
                ah[s][kc][i] = f2bf_bits(f[i]);
                al[s][kc][i] = f2bf_bits(f[i] - bf_hi_f(f[i]));
            }
        }
    }

    // top-2 state in max-space (v = -dist); b1 >= b2 invariant
    float b1[2][4], b2[2][4]; int i1[2][4];
    #pragma unroll
    for (int s = 0; s < 2; ++s)
        #pragma unroll
        for (int r = 0; r < 4; ++r) { b1[s][r] = -3.0e38f; b2[s][r] = -3.0e38f; i1[s][r] = 0; }

    // this wave's staging window: src and dst are both uniform + lane*16
    const int combo0 = wave * 4;
    const char* gsrc0 = (const char*)esw + (size_t)kbase * 256
                        + combo0 * 1024 + lane * 16;
    // prologue: issue stage 0 -> buf 0
    #pragma unroll
    for (int it = 0; it < 4; ++it)
        gload_lds16(gsrc0 + it * 1024, (char*)&es[0][0] + (combo0 + it) * 1024);

    for (int nb = 0; nb < NSTG; ++nb) {
        const int cur = nb & 1;
        const int n0 = kbase + nb * NSTAGE;
        __syncthreads();   // vmcnt drained: buf[cur] complete; buf[cur^1] reusable
        if (nb + 1 < NSTG) {
            const char* gsrc = gsrc0 + (size_t)(nb + 1) * (NSTAGE * 256);
            #pragma unroll
            for (int it = 0; it < 4; ++it)
                gload_lds16(gsrc + it * 1024,
                            (char*)&es[cur ^ 1][0] + (combo0 + it) * 1024);
        }
        // per-stage -se prefetch (L1/L2-resident, hidden under MFMA)
        float nse[4];
        #pragma unroll
        for (int sub = 0; sub < 4; ++sub) nse[sub] = -se_half[n0 + sub * 16 + col];

        const short* esb = es[cur];
        #pragma unroll
        for (int sub = 0; sub < 4; ++sub) {
            const short* base = esb + sub * 2048;
            const bf16x8 bh0 = *(const bf16x8*)(base + 0 * 512 + lane * 8);
            const bf16x8 bh1 = *(const bf16x8*)(base + 1 * 512 + lane * 8);
            const bf16x8 bl0 = *(const bf16x8*)(base + 2 * 512 + lane * 8);
            const bf16x8 bl1 = *(const bf16x8*)(base + 3 * 512 + lane * 8);
            const float m = nse[sub];
            const int nglob = n0 + sub * 16 + col;
            #pragma unroll
            for (int s = 0; s < 2; ++s) {
                // single 6-deep chain seeded with C = {-sse}: acc = dot - sse
                f32x4 acc = {m, m, m, m};
                acc = __builtin_amdgcn_mfma_f32_16x16x32_bf16(ah[s][0], bh0, acc, 0, 0, 0);
                acc = __builtin_amdgcn_mfma_f32_16x16x32_bf16(ah[s][0], bl0, acc, 0, 0, 0);
                acc = __builtin_amdgcn_mfma_f32_16x16x32_bf16(al[s][0], bh0, acc, 0, 0, 0);
                acc = __builtin_amdgcn_mfma_f32_16x16x32_bf16(ah[s][1], bh1, acc, 0, 0, 0);
                acc = __builtin_amdgcn_mfma_f32_16x16x32_bf16(ah[s][1], bl1, acc, 0, 0, 0);
                acc = __builtin_amdgcn_mfma_f32_16x16x32_bf16(al[s][1], bh1, acc, 0, 0, 0);
                #pragma unroll
                for (int r = 0; r < 4; ++r) {
                    const float v = acc[r];                      // -dist
                    // b1>=b2 invariant -> med3 == new 2nd-max (1 instr)
                    b2[s][r] = __builtin_amdgcn_fmed3f(v, b2[s][r], b1[s][r]);
                    const bool t = v > b1[s][r];                 // strict >, n ascending
                    b1[s][r] = fmaxf(b1[s][r], v);
                    i1[s][r] = t ? nglob : i1[s][r];
                }
            }
        }
    }

    // merge top-2 across the 16 col-lanes (xor 1,2,4,8 stays inside quad group)
    #pragma unroll
    for (int m = 1; m <= 8; m <<= 1) {
        #pragma unroll
        for (int s = 0; s < 2; ++s)
            #pragma unroll
            for (int r = 0; r < 4; ++r) {
                const float ob1 = __shfl_xor(b1[s][r], m, 64);
                const int   oi1 = __shfl_xor(i1[s][r], m, 64);
                const float ob2 = __shfl_xor(b2[s][r], m, 64);
                const bool take = (ob1 > b1[s][r]) || (ob1 == b1[s][r] && oi1 < i1[s][r]);
                b2[s][r] = fmaxf(fmaxf(b2[s][r], ob2), fminf(b1[s][r], ob1));
                b1[s][r] = take ? ob1 : b1[s][r];
                i1[s][r] = take ? oi1 : i1[s][r];
            }
    }
    if (col == 0) {
        #pragma unroll
        for (int s = 0; s < 2; ++s)
            #pragma unroll
            for (int r = 0; r < 4; ++r) {
                const int p = p0 + s * 16 + quad * 4 + r;   // C/D row = quad*4 + r
                pv[g * NPIX + p] = make_float2(b1[s][r], b2[s][r]);
                pi[g * NPIX + p] = (unsigned)i1[s][r];
            }
    }
}

// ---------------- merge: combine KSPLIT partials (max-space), flag -----------
__global__ __launch_bounds__(256) void k_merge(const float2* __restrict__ pv,
                                               const unsigned* __restrict__ pi,
                                               unsigned* __restrict__ idx_arr,
                                               unsigned* __restrict__ list,
                                               unsigned* __restrict__ counter,
                                               unsigned long long* __restrict__ packed) {
    const int p = blockIdx.x * 256 + threadIdx.x;
    float2 v[KSPLIT]; unsigned ix[KSPLIT];
    #pragma unroll
    for (int gg = 0; gg < KSPLIT; ++gg) { v[gg] = pv[gg * NPIX + p]; ix[gg] = pi[gg * NPIX + p]; }
    // ascending group order + strict > == np first-occurrence tie semantics
    float b1 = v[0].x; unsigned i1 = ix[0]; int win = 0;
    #pragma unroll
    for (int gg = 1; gg < KSPLIT; ++gg)
        if (v[gg].x > b1) { b1 = v[gg].x; i1 = ix[gg]; win = gg; }
    float b2 = -3.0e38f;
    #pragma unroll
    for (int gg = 0; gg < KSPLIT; ++gg) {
        b2 = fmaxf(b2, v[gg].y);
        if (gg != win) b2 = fmaxf(b2, v[gg].x);
    }
    const bool fl = (b1 - b2 < MARGIN);   // dist2 - dist1 == b1 - b2
    idx_arr[p] = i1 | (fl ? 0x80000000u : 0u);
    if (fl) {
        packed[p] = ~0ull;
        const unsigned pos = atomicAdd(counter, 1u);
        if (pos < NPIX) list[pos] = p;
    }
}

// ---------------- recheck: exact fp32 argmin for flagged pixels --------------
// item = (flagged pixel, 512-code chunk). Coalesced: 4 codes x 16 lanes per
// b128 (contiguous 1KB from L2-resident e_norm); intra-16-lane shfl reduce.
__global__ __launch_bounds__(256) void k_recheck(const float* __restrict__ zn,
                                                 const float* __restrict__ e_norm,
                                                 const float* __restrict__ se_half,
                                                 const unsigned* __restrict__ list,
                                                 const unsigned* __restrict__ counter,
                                                 unsigned long long* __restrict__ packed) {
    const int lane  = threadIdx.x & 63;
    const int k     = lane >> 4;        // code-in-group 0..3
    const int m     = lane & 15;        // c4 index 0..15
    const int wglob = (blockIdx.x * 256 + threadIdx.x) >> 6;
    const int nwav  = (gridDim.x * 256) >> 6;
    int cnt = (int)*counter; if (cnt > NPIX) cnt = NPIX;
    const int nitems = cnt * 16;
    const float4* e4 = (const float4*)e_norm;

    for (int item = wglob; item < nitems; item += nwav) {
        const int p     = (int)list[item >> 4];
        const int chunk = item & 15;
        const float4 zv = *(const float4*)(zn + p * EDIM + m * 4);  // bcast/16 lanes
        float best = 3.0e38f; int bidx = 0;
        #pragma unroll 2
        for (int t = 0; t < 128; ++t) {                // 4 codes per iteration
            const int n = chunk * 512 + t * 4 + k;     // lane's code this iter
            const float4 ev = e4[n * 16 + m];          // lane-linear: 1KB contiguous
            float s = fmaf(zv.w, ev.w, fmaf(zv.z, ev.z,
                      fmaf(zv.y, ev.y, zv.x * ev.x)));
            s += __shfl_xor(s, 1, 64); s += __shfl_xor(s, 2, 64);
            s += __shfl_xor(s, 4, 64); s += __shfl_xor(s, 8, 64);
            const float d = se_half[n] - s;            // all 16 lanes same d
            if (d < best) { best = d; bidx = n; }      // lane's codes ascending
        }
        #pragma unroll
        for (int mm = 1; mm <= 32; mm <<= 1) {         // wave first-min
            const float ob = __shfl_xor(best, mm, 64);
            const int   oi = __shfl_xor(bidx, mm, 64);
            if (ob < best || (ob == best && oi < bidx)) { best = ob; bidx = oi; }
        }
        if (lane == 0) {
            const unsigned long long key =
                ((unsigned long long)order_u32(best) << 32) | (unsigned)bidx;
            atomicMin(&packed[p], key);
        }
    }
}

// ---------------- finalize: write indices + gather z_q (4 thr/pixel) ---------
__global__ __launch_bounds__(256) void k_finalize(const unsigned* __restrict__ idx_arr,
                                                  const unsigned long long* __restrict__ packed,
                                                  const float* __restrict__ e_norm,
                                                  float* __restrict__ out) {
    const int pl = threadIdx.x & 63;
    const int q  = threadIdx.x >> 6;                  // channel quarter 0..3
    const int p  = blockIdx.x * 64 + pl;
    const unsigned v = idx_arr[p];
    const int bidx = (v & 0x80000000u) ? (int)(packed[p] & 0xFFFFFFFFull)
                                       : (int)v;
    if (q == 0) out[NPIX * EDIM + p] = (float)bidx;
    const int b = p >> 12, hw = p & (HW - 1);
    float* op = out + b * (EDIM * HW) + hw;
    const float4* ep4 = (const float4*)(e_norm + bidx * EDIM + q * 16);
    #pragma unroll
    for (int j = 0; j < 4; ++j) {
        const float4 e = ep4[j];
        const int c = q * 16 + j * 4;
        op[(c + 0) * HW] = e.x; op[(c + 1) * HW] = e.y;   // coalesced per c
        op[(c + 2) * HW] = e.z; op[(c + 3) * HW] = e.w;
    }
}

extern "C" void kernel_launch(void* const* d_in, const int* in_sizes, int n_in,
                              void* d_out, int out_size, void* d_ws, size_t ws_size,
                              hipStream_t stream) {
    const float* z   = (const float*)d_in[0];
    const float* emb = (const float*)d_in[1];
    float* out = (float*)d_out;

    // workspace layout (~15.6 MB)
    float* e_norm  = (float*)d_ws;                       // 2 MB
    float* se_half = e_norm + NE * EDIM;                 // 32 KB
    short* esw = (short*)(se_half + NE);                 // 2 MB (swizzled hi+lo)
    float* zn = (float*)(esw + NE * EDIM * 2);           // 8 MB
    unsigned* idx_arr = (unsigned*)(zn + NPIX * EDIM);   // 128 KB
    unsigned* list    = idx_arr + NPIX;                  // 128 KB
    unsigned* counter = list + NPIX;                     // 4 B (+pad)
    unsigned long long* packed = (unsigned long long*)(counter + 64); // 256 KB
    float2*   pv = (float2*)(packed + NPIX);             // 2 MB
    unsigned* pi = (unsigned*)(pv + KSPLIT * NPIX);      // 1 MB

    k_prep<<<NE / 4 + NPIX / 256, 256, 0, stream>>>(emb, z, e_norm, se_half,
                                                    esw, zn, counter);
    k_mfma<<<dim3(NPIX / 128, KSPLIT), 256, 0, stream>>>(zn, esw, se_half, pv, pi);
    k_merge<<<NPIX / 256, 256, 0, stream>>>(pv, pi, idx_arr, list, counter, packed);
    k_recheck<<<1024, 256, 0, stream>>>(zn, e_norm, se_half, list, counter, packed);
    k_finalize<<<NPIX / 64, 256, 0, stream>>>(idx_arr, packed, e_norm, out);
}